// Round 10
// baseline (316.863 us; speedup 1.0000x reference)
//
#include <hip/hip_runtime.h>
#include <cstdint>
#include <cstddef>

#define NB 8
#define NL 2048
#define TOPK 30
#define NH 128
#define CAND_CAP 256

typedef unsigned long long ull;
typedef __attribute__((ext_vector_type(8))) short short8v;   // 8 bf16
typedef __attribute__((ext_vector_type(4))) float f32x4;

__device__ __forceinline__ short f2bf(float f) {
    unsigned int b = __float_as_uint(f);
    b += 0x7fffu + ((b >> 16) & 1u);          // round-to-nearest-even
    return (short)(b >> 16);
}

// ---------------------------------------------------------------------------
// K0: pack CA coords + mask into SoA float4 (x,y,z,m) for coalesced topk loads.
// ---------------------------------------------------------------------------
__global__ __launch_bounds__(256) void xpose_kernel(
    const float* __restrict__ X, const float* __restrict__ mask,
    float4* __restrict__ P)
{
    int t = blockIdx.x * blockDim.x + threadIdx.x;
    if (t >= NB * NL) return;
    const float* p = X + (size_t)t * 12 + 3;
    P[t] = make_float4(p[0], p[1], p[2], mask[t]);
}

// ---------------------------------------------------------------------------
// K1 (v6): one WAVE per row, register-resident.
// vs v5: __launch_bounds__(256,6) -> VGPR cap ~85 -> 6 waves/SIMD (TLP);
// 4-way split accumulator chains (ILP); P5 rank loop unrolled x4 with
// batched LDS reads (sentinel ~0ULL pads are rank-neutral).
// Selection exactness unchanged: key=(bits<<32)|j == lax.top_k stable order;
// threshold = 30th-smallest of 64 lane-minima (bitonic), provably >= true
// 30th element; exact fallback if candidates overflow.
// ---------------------------------------------------------------------------
__global__ __launch_bounds__(256, 6) void topk_kernel(
    const float4* __restrict__ P,
    float* __restrict__ eidx, float* __restrict__ dnb)
{
    __shared__ ull cand[4][CAND_CAP];              // 8 KB

    const int tid = threadIdx.x;
    const int wv  = tid >> 6;
    const int ln  = tid & 63;
    const int row = blockIdx.x * 4 + wv;           // 4 consecutive rows/block
    const int b   = row >> 11;
    const int i   = row & (NL - 1);

    const float4* Pb = P + (size_t)b * NL;
    const float4 pi = Pb[i];
    const float xi = pi.x, yi = pi.y, zi = pi.z, mi = pi.w;

    // ---- P1: distances once; mask flag in sign bit; 4-way max chains ----
    unsigned int u[32];
    float lm0 = 0.0f, lm1 = 0.0f, lm2 = 0.0f, lm3 = 0.0f;
    #pragma unroll
    for (int t = 0; t < 32; t += 4) {
        #pragma unroll
        for (int q = 0; q < 4; ++q) {
            const float4 pj = Pb[ln + 64 * (t + q)];
            float dx = xi - pj.x;
            float dy = yi - pj.y;
            float dz = zi - pj.z;
            float s = __fadd_rn(__fmul_rn(dx, dx), __fmul_rn(dy, dy));
            s = __fadd_rn(s, __fmul_rn(dz, dz));
            s = __fadd_rn(s, 1e-6f);
            float m2 = __fmul_rn(pj.w, mi);        // binary mask: 0 or 1
            float d  = __fmul_rn(m2, __fsqrt_rn(s));
            u[t + q] = __float_as_uint(d) | ((m2 == 0.0f) ? 0x80000000u : 0u);
            if      (q == 0) lm0 = fmaxf(lm0, d);
            else if (q == 1) lm1 = fmaxf(lm1, d);
            else if (q == 2) lm2 = fmaxf(lm2, d);
            else             lm3 = fmaxf(lm3, d);
        }
    }
    float lmax = fmaxf(fmaxf(lm0, lm1), fmaxf(lm2, lm3));
    #pragma unroll
    for (int off = 32; off; off >>= 1) lmax = fmaxf(lmax, __shfl_xor(lmax, off));
    const unsigned int DMB = __float_as_uint(__fadd_rn(lmax, 1.0f));

    // ---- P2: adjusted bits via select + per-lane min (4-way chains) ----
    unsigned int um0 = 0xFFFFFFFFu, um1 = 0xFFFFFFFFu,
                 um2 = 0xFFFFFFFFu, um3 = 0xFFFFFFFFu;
    #pragma unroll
    for (int t = 0; t < 32; t += 4) {
        unsigned int b0 = (u[t+0] & 0x80000000u) ? DMB : u[t+0];
        unsigned int b1 = (u[t+1] & 0x80000000u) ? DMB : u[t+1];
        unsigned int b2 = (u[t+2] & 0x80000000u) ? DMB : u[t+2];
        unsigned int b3 = (u[t+3] & 0x80000000u) ? DMB : u[t+3];
        u[t+0] = b0; u[t+1] = b1; u[t+2] = b2; u[t+3] = b3;
        um0 = min(um0, b0); um1 = min(um1, b1);
        um2 = min(um2, b2); um3 = min(um3, b3);
    }
    unsigned int umin = min(min(um0, um1), min(um2, um3));

    // ---- P3: bitonic sort of 64 lane-minima -> threshold T at rank 29 ----
    unsigned int v = umin;
    #pragma unroll
    for (int k = 2; k <= 64; k <<= 1) {
        #pragma unroll
        for (int j = k >> 1; j > 0; j >>= 1) {
            unsigned int o = __shfl_xor(v, j);
            bool asc   = ((ln & k) == 0);
            bool lower = ((ln & j) == 0);
            v = (lower == asc) ? min(v, o) : max(v, o);
        }
    }
    const unsigned int T = __shfl(v, TOPK - 1);

    // ---- P4: ordered ballot compaction (index-sorted: t outer, lane inner) ----
    unsigned int base = 0;
    #pragma unroll
    for (int t = 0; t < 32; ++t) {
        bool act = u[t] <= T;
        ull m = __ballot(act);
        if (act) {
            unsigned int pos = base + (unsigned)__popcll(m & ((1ull << ln) - 1ull));
            if (pos < CAND_CAP)
                cand[wv][pos] = ((ull)u[t] << 32) | (unsigned)(ln + 64 * t);
        }
        base += (unsigned)__popcll(m);
    }
    const unsigned int cnt = base;

    float* eo  = eidx + (size_t)row * TOPK;
    float* dno = dnb  + (size_t)row * TOPK;

    if (cnt <= CAND_CAP) {
        // ---- P5: rank-based exact selection, unrolled x4 ----
        ull k0 = ((unsigned)ln        < cnt) ? cand[wv][ln]        : ~0ULL;
        ull k1 = ((unsigned)ln +  64u < cnt) ? cand[wv][ln +  64]  : ~0ULL;
        ull k2 = ((unsigned)ln + 128u < cnt) ? cand[wv][ln + 128]  : ~0ULL;
        ull k3 = ((unsigned)ln + 192u < cnt) ? cand[wv][ln + 192]  : ~0ULL;
        int r0 = 0, r1 = 0, r2 = 0, r3 = 0;
        for (unsigned int p = 0; p < cnt; p += 4) {
            ull c0 = cand[wv][p];
            ull c1 = (p + 1 < cnt) ? cand[wv][p + 1] : ~0ULL;
            ull c2 = (p + 2 < cnt) ? cand[wv][p + 2] : ~0ULL;
            ull c3 = (p + 3 < cnt) ? cand[wv][p + 3] : ~0ULL;
            r0 += (c0 < k0) + (c1 < k0) + (c2 < k0) + (c3 < k0);
            r1 += (c0 < k1) + (c1 < k1) + (c2 < k1) + (c3 < k1);
            r2 += (c0 < k2) + (c1 < k2) + (c2 < k2) + (c3 < k2);
            r3 += (c0 < k3) + (c1 < k3) + (c2 < k3) + (c3 < k3);
        }
        if (r0 < TOPK) { eo[r0] = (float)(unsigned)(k0 & 0xFFFFFFFFu); dno[r0] = __uint_as_float((unsigned)(k0 >> 32)); }
        if (r1 < TOPK) { eo[r1] = (float)(unsigned)(k1 & 0xFFFFFFFFu); dno[r1] = __uint_as_float((unsigned)(k1 >> 32)); }
        if (r2 < TOPK) { eo[r2] = (float)(unsigned)(k2 & 0xFFFFFFFFu); dno[r2] = __uint_as_float((unsigned)(k2 >> 32)); }
        if (r3 < TOPK) { eo[r3] = (float)(unsigned)(k3 & 0xFFFFFFFFu); dno[r3] = __uint_as_float((unsigned)(k3 >> 32)); }
    } else {
        // ---- fallback: wave-iterative exact argmin from registers (rare) ----
        ull last = 0ULL;
        for (int k = 0; k < TOPK; ++k) {
            ull best = ~0ULL;
            #pragma unroll
            for (int t = 0; t < 32; ++t) {
                ull key = ((ull)u[t] << 32) | (unsigned)(ln + 64 * t);
                if (key > last && key < best) best = key;
            }
            #pragma unroll
            for (int off = 32; off; off >>= 1) {
                ull o = __shfl_xor(best, off);
                if (o < best) best = o;
            }
            if (ln == 0) {
                eo[k]  = (float)(unsigned)(best & 0xFFFFFFFFu);
                dno[k] = __uint_as_float((unsigned)(best >> 32));
            }
            last = best;
        }
    }
}

// ---------------------------------------------------------------------------
// K2 (v2): edge features -> 32x128 matmul (MFMA bf16) -> LayerNorm -> E.
// (unchanged from R9)
// ---------------------------------------------------------------------------
__global__ __launch_bounds__(256) void edge_kernel(
    const float* __restrict__ eidx, const float* __restrict__ dnb,
    const float* __restrict__ We, const float* __restrict__ be,
    const float* __restrict__ ge, const float* __restrict__ bte,
    float* __restrict__ E)
{
    const int lane = threadIdx.x & 63;
    const int c    = lane & 15;        // edge within tile / A-row (h_low)
    const int g    = lane >> 4;        // k-group
    const int wid  = (int)((blockIdx.x * blockDim.x + threadIdx.x) >> 6);
    const int nw   = (int)((gridDim.x * blockDim.x) >> 6);

    short8v W[8];
    #pragma unroll
    for (int t = 0; t < 8; ++t)
        #pragma unroll
        for (int e = 0; e < 8; ++e)
            W[t][e] = f2bf(We[(g * 8 + e) * NH + t * 16 + c]);

    float fcs[8];
    #pragma unroll
    for (int e = 0; e < 8; ++e) {
        if (g < 2) fcs[e] = expf((float)(2 * e) * -0.57564627f);  // ln(1e4)/16
        else       fcs[e] = (float)((g - 2) * 8 + e) * (20.0f / 15.0f);
    }

    const int ntiles = NB * NL * TOPK / 16;
    for (int tile = wid; tile < ntiles; tile += nw) {
        const int e0   = tile * 16;
        const int edge = e0 + c;
        const float fidx = eidx[edge];
        const float Dv   = dnb[edge];
        const int   row  = edge / TOPK;
        const float d    = fidx - (float)(row & (NL - 1));

        short8v F;
        if (g == 0) {
            #pragma unroll
            for (int e = 0; e < 8; ++e) F[e] = f2bf(cosf(d * fcs[e]));
        } else if (g == 1) {
            #pragma unroll
            for (int e = 0; e < 8; ++e) F[e] = f2bf(sinf(d * fcs[e]));
        } else {
            #pragma unroll
            for (int e = 0; e < 8; ++e) {
                float tt = (Dv - fcs[e]) * 0.8f;
                F[e] = f2bf(expf(-tt * tt));
            }
        }

        f32x4 acc[8];
        const f32x4 zero = {0.0f, 0.0f, 0.0f, 0.0f};
        #pragma unroll
        for (int t = 0; t < 8; ++t)
            acc[t] = __builtin_amdgcn_mfma_f32_16x16x32_bf16(W[t], F, zero, 0, 0, 0);

        float s = 0.0f, s2 = 0.0f;
        #pragma unroll
        for (int t = 0; t < 8; ++t) {
            const f32x4 b4 = *(const f32x4*)&be[t * 16 + g * 4];
            #pragma unroll
            for (int j = 0; j < 4; ++j) {
                float vv = acc[t][j] + b4[j];
                acc[t][j] = vv;
                s  += vv;
                s2 = fmaf(vv, vv, s2);
            }
        }
        s  += __shfl_xor(s, 16);  s  += __shfl_xor(s, 32);
        s2 += __shfl_xor(s2, 16); s2 += __shfl_xor(s2, 32);
        const float mean = s * (1.0f / 128.0f);
        const float var  = fmaxf(s2 * (1.0f / 128.0f) - mean * mean, 0.0f);
        const float inv  = rsqrtf(var + 1e-5f);

        float* const Eo = E + (size_t)edge * NH;
        #pragma unroll
        for (int t = 0; t < 8; ++t) {
            const f32x4 g4  = *(const f32x4*)&ge [t * 16 + g * 4];
            const f32x4 bt4 = *(const f32x4*)&bte[t * 16 + g * 4];
            f32x4 o;
            #pragma unroll
            for (int j = 0; j < 4; ++j)
                o[j] = (acc[t][j] - mean) * inv * g4[j] + bt4[j];
            __builtin_nontemporal_store(o, (f32x4*)&Eo[t * 16 + g * 4]);
        }
    }
}

// ---------------------------------------------------------------------------
// K3: FUSED dihedral + node matmul + LayerNorm -> V. One wave per node.
// (unchanged from R9)
// ---------------------------------------------------------------------------
__device__ __forceinline__ void loadPt(const float* XB, int t, float v[3]) {
    int r = t / 3, a = t - 3 * r;
    const float* p = XB + ((size_t)r * 4 + a) * 3;
    v[0] = p[0]; v[1] = p[1]; v[2] = p[2];
}
__device__ __forceinline__ void unit3(float v[3]) {
    float n = sqrtf(v[0]*v[0] + v[1]*v[1] + v[2]*v[2]) + 1e-8f;
    v[0] /= n; v[1] /= n; v[2] /= n;
}
__device__ __forceinline__ void cross3(const float a[3], const float b[3], float o[3]) {
    o[0] = a[1]*b[2] - a[2]*b[1];
    o[1] = a[2]*b[0] - a[0]*b[2];
    o[2] = a[0]*b[1] - a[1]*b[0];
}

__global__ __launch_bounds__(256) void vn_kernel(
    const float* __restrict__ X, const float* __restrict__ Wn,
    const float* __restrict__ bn, const float* __restrict__ gn,
    const float* __restrict__ btn, float* __restrict__ V)
{
    const int ln   = threadIdx.x & 63;
    const int wv   = threadIdx.x >> 6;
    const int node = blockIdx.x * 4 + wv;
    const int b = node >> 11, i = node & (NL - 1);
    const float* XB = X + (size_t)b * NL * 12;

    float fc = 1.0f, fs = 0.0f;                    // pad: cos(0), sin(0)
    if (ln < 3) {
        int t = 3 * i - 1 + ln;
        float an = 0.0f;
        if (t >= 0 && t <= 3 * NL - 4) {
            float p0[3], p1[3], p2[3], p3[3];
            loadPt(XB, t, p0); loadPt(XB, t + 1, p1);
            loadPt(XB, t + 2, p2); loadPt(XB, t + 3, p3);
            float u2[3], u1[3], u0[3];
            for (int cc = 0; cc < 3; ++cc) {
                u2[cc] = p1[cc] - p0[cc];
                u1[cc] = p2[cc] - p1[cc];
                u0[cc] = p3[cc] - p2[cc];
            }
            unit3(u2); unit3(u1); unit3(u0);
            float n2[3], n1[3];
            cross3(u2, u1, n2); cross3(u1, u0, n1);
            unit3(n2); unit3(n1);
            float cosD = n2[0]*n1[0] + n2[1]*n1[1] + n2[2]*n1[2];
            cosD = fminf(fmaxf(cosD, -1.0f + 1e-7f), 1.0f - 1e-7f);
            float sg = u2[0]*n1[0] + u2[1]*n1[1] + u2[2]*n1[2];
            float sgn = (sg > 0.0f) ? 1.0f : ((sg < 0.0f) ? -1.0f : 0.0f);
            an = sgn * acosf(cosD);
        }
        fc = cosf(an); fs = sinf(an);
    }
    float f[6];
    f[0] = __shfl(fc, 0); f[1] = __shfl(fc, 1); f[2] = __shfl(fc, 2);
    f[3] = __shfl(fs, 0); f[4] = __shfl(fs, 1); f[5] = __shfl(fs, 2);

    const int h0 = ln, h1 = ln + 64;
    float a0 = bn[h0], a1 = bn[h1];
    #pragma unroll
    for (int j = 0; j < 6; ++j) {
        a0 = fmaf(f[j], Wn[j * NH + h0], a0);
        a1 = fmaf(f[j], Wn[j * NH + h1], a1);
    }
    float s  = a0 + a1;
    float s2 = fmaf(a0, a0, a1 * a1);
    #pragma unroll
    for (int off = 32; off; off >>= 1) {
        s  += __shfl_xor(s, off);
        s2 += __shfl_xor(s2, off);
    }
    float mean = s * (1.0f / 128.0f);
    float var  = fmaxf(s2 * (1.0f / 128.0f) - mean * mean, 0.0f);
    float inv  = rsqrtf(var + 1e-5f);
    float* o = V + (size_t)node * NH;
    o[h0] = (a0 - mean) * inv * gn[h0] + btn[h0];
    o[h1] = (a1 - mean) * inv * gn[h1] + btn[h1];
}

extern "C" void kernel_launch(void* const* d_in, const int* in_sizes, int n_in,
                              void* d_out, int out_size, void* d_ws, size_t ws_size,
                              hipStream_t stream)
{
    const float* X    = (const float*)d_in[0];
    const float* mask = (const float*)d_in[1];
    const float* Wn   = (const float*)d_in[2];
    const float* bn   = (const float*)d_in[3];
    const float* We   = (const float*)d_in[4];
    const float* be   = (const float*)d_in[5];
    const float* gn   = (const float*)d_in[6];
    const float* btn  = (const float*)d_in[7];
    const float* ge   = (const float*)d_in[8];
    const float* bte  = (const float*)d_in[9];

    float* out = (float*)d_out;
    float* V   = out;                                   // (8,2048,128)
    float* E   = V  + (size_t)NB * NL * NH;             // (8,2048,30,128)
    float* EI  = E  + (size_t)NB * NL * TOPK * NH;      // (8,2048,30) as float

    float4* P  = (float4*)d_ws;                         // SoA (x,y,z,m), 256 KB
    float* dnb = (float*)d_ws + 4 * (size_t)NB * NL;    // D_neighbors scratch

    hipLaunchKernelGGL(xpose_kernel, dim3((NB * NL + 255)/256), dim3(256), 0, stream,
                       X, mask, P);
    hipLaunchKernelGGL(topk_kernel,  dim3(NB * NL / 4),         dim3(256), 0, stream,
                       P, EI, dnb);
    hipLaunchKernelGGL(vn_kernel,    dim3(NB * NL / 4),         dim3(256), 0, stream,
                       X, Wn, bn, gn, btn, V);
    // ATTRIBUTION PROBE: edge launched twice (pure function of EI/dnb ->
    // idempotent). dur(R10) = base + T_edge; R11 drops the dup to read
    // T_edge exactly AND T_topk_v6 = dur(R11) - 103.1.
    hipLaunchKernelGGL(edge_kernel,  dim3(1920),                dim3(256), 0, stream,
                       EI, dnb, We, be, ge, bte, E);
    hipLaunchKernelGGL(edge_kernel,  dim3(1920),                dim3(256), 0, stream,
                       EI, dnb, We, be, ge, bte, E);
}

// Round 11
// 170.438 us; speedup vs baseline: 1.8591x; 1.8591x over previous
//
#include <hip/hip_runtime.h>
#include <cstdint>
#include <cstddef>

#define NB 8
#define NL 2048
#define TOPK 30
#define NH 128
#define CAND_CAP 256

typedef unsigned long long ull;
typedef __attribute__((ext_vector_type(8))) short short8v;   // 8 bf16
typedef __attribute__((ext_vector_type(4))) float f32x4;

__device__ __forceinline__ short f2bf(float f) {
    unsigned int b = __float_as_uint(f);
    b += 0x7fffu + ((b >> 16) & 1u);          // round-to-nearest-even
    return (short)(b >> 16);
}

// ---------------------------------------------------------------------------
// K0: pack CA coords + mask into SoA float4 (x,y,z,m) for coalesced topk loads.
// ---------------------------------------------------------------------------
__global__ __launch_bounds__(256) void xpose_kernel(
    const float* __restrict__ X, const float* __restrict__ mask,
    float4* __restrict__ P)
{
    int t = blockIdx.x * blockDim.x + threadIdx.x;
    if (t >= NB * NL) return;
    const float* p = X + (size_t)t * 12 + 3;
    P[t] = make_float4(p[0], p[1], p[2], mask[t]);
}

// ---------------------------------------------------------------------------
// K1 (v7): v5's register budget (NO occupancy cap -- R10 showed
// __launch_bounds__(256,6) forces u[32] to scratch: 226MB fetch, 3.7x slower)
// + v6's harmless ILP (4-way split accumulator chains, P5 rank loop x4).
// Selection exactness unchanged: key=(bits<<32)|j == lax.top_k stable order.
// ---------------------------------------------------------------------------
__global__ __launch_bounds__(256) void topk_kernel(
    const float4* __restrict__ P,
    float* __restrict__ eidx, float* __restrict__ dnb)
{
    __shared__ ull cand[4][CAND_CAP];              // 8 KB

    const int tid = threadIdx.x;
    const int wv  = tid >> 6;
    const int ln  = tid & 63;
    const int row = blockIdx.x * 4 + wv;           // 4 consecutive rows/block
    const int b   = row >> 11;
    const int i   = row & (NL - 1);

    const float4* Pb = P + (size_t)b * NL;
    const float4 pi = Pb[i];
    const float xi = pi.x, yi = pi.y, zi = pi.z, mi = pi.w;

    // ---- P1: distances once; mask flag in sign bit; 4-way max chains ----
    unsigned int u[32];
    float lm0 = 0.0f, lm1 = 0.0f, lm2 = 0.0f, lm3 = 0.0f;
    #pragma unroll
    for (int t = 0; t < 32; t += 4) {
        #pragma unroll
        for (int q = 0; q < 4; ++q) {
            const float4 pj = Pb[ln + 64 * (t + q)];
            float dx = xi - pj.x;
            float dy = yi - pj.y;
            float dz = zi - pj.z;
            float s = __fadd_rn(__fmul_rn(dx, dx), __fmul_rn(dy, dy));
            s = __fadd_rn(s, __fmul_rn(dz, dz));
            s = __fadd_rn(s, 1e-6f);
            float m2 = __fmul_rn(pj.w, mi);        // binary mask: 0 or 1
            float d  = __fmul_rn(m2, __fsqrt_rn(s));
            u[t + q] = __float_as_uint(d) | ((m2 == 0.0f) ? 0x80000000u : 0u);
            if      (q == 0) lm0 = fmaxf(lm0, d);
            else if (q == 1) lm1 = fmaxf(lm1, d);
            else if (q == 2) lm2 = fmaxf(lm2, d);
            else             lm3 = fmaxf(lm3, d);
        }
    }
    float lmax = fmaxf(fmaxf(lm0, lm1), fmaxf(lm2, lm3));
    #pragma unroll
    for (int off = 32; off; off >>= 1) lmax = fmaxf(lmax, __shfl_xor(lmax, off));
    const unsigned int DMB = __float_as_uint(__fadd_rn(lmax, 1.0f));

    // ---- P2: adjusted bits via select + per-lane min (4-way chains) ----
    unsigned int um0 = 0xFFFFFFFFu, um1 = 0xFFFFFFFFu,
                 um2 = 0xFFFFFFFFu, um3 = 0xFFFFFFFFu;
    #pragma unroll
    for (int t = 0; t < 32; t += 4) {
        unsigned int b0 = (u[t+0] & 0x80000000u) ? DMB : u[t+0];
        unsigned int b1 = (u[t+1] & 0x80000000u) ? DMB : u[t+1];
        unsigned int b2 = (u[t+2] & 0x80000000u) ? DMB : u[t+2];
        unsigned int b3 = (u[t+3] & 0x80000000u) ? DMB : u[t+3];
        u[t+0] = b0; u[t+1] = b1; u[t+2] = b2; u[t+3] = b3;
        um0 = min(um0, b0); um1 = min(um1, b1);
        um2 = min(um2, b2); um3 = min(um3, b3);
    }
    unsigned int umin = min(min(um0, um1), min(um2, um3));

    // ---- P3: bitonic sort of 64 lane-minima -> threshold T at rank 29 ----
    unsigned int v = umin;
    #pragma unroll
    for (int k = 2; k <= 64; k <<= 1) {
        #pragma unroll
        for (int j = k >> 1; j > 0; j >>= 1) {
            unsigned int o = __shfl_xor(v, j);
            bool asc   = ((ln & k) == 0);
            bool lower = ((ln & j) == 0);
            v = (lower == asc) ? min(v, o) : max(v, o);
        }
    }
    const unsigned int T = __shfl(v, TOPK - 1);

    // ---- P4: ordered ballot compaction (index-sorted: t outer, lane inner) ----
    unsigned int base = 0;
    #pragma unroll
    for (int t = 0; t < 32; ++t) {
        bool act = u[t] <= T;
        ull m = __ballot(act);
        if (act) {
            unsigned int pos = base + (unsigned)__popcll(m & ((1ull << ln) - 1ull));
            if (pos < CAND_CAP)
                cand[wv][pos] = ((ull)u[t] << 32) | (unsigned)(ln + 64 * t);
        }
        base += (unsigned)__popcll(m);
    }
    const unsigned int cnt = base;

    float* eo  = eidx + (size_t)row * TOPK;
    float* dno = dnb  + (size_t)row * TOPK;

    if (cnt <= CAND_CAP) {
        // ---- P5: rank-based exact selection, unrolled x4 ----
        ull k0 = ((unsigned)ln        < cnt) ? cand[wv][ln]        : ~0ULL;
        ull k1 = ((unsigned)ln +  64u < cnt) ? cand[wv][ln +  64]  : ~0ULL;
        ull k2 = ((unsigned)ln + 128u < cnt) ? cand[wv][ln + 128]  : ~0ULL;
        ull k3 = ((unsigned)ln + 192u < cnt) ? cand[wv][ln + 192]  : ~0ULL;
        int r0 = 0, r1 = 0, r2 = 0, r3 = 0;
        for (unsigned int p = 0; p < cnt; p += 4) {
            ull c0 = cand[wv][p];
            ull c1 = (p + 1 < cnt) ? cand[wv][p + 1] : ~0ULL;
            ull c2 = (p + 2 < cnt) ? cand[wv][p + 2] : ~0ULL;
            ull c3 = (p + 3 < cnt) ? cand[wv][p + 3] : ~0ULL;
            r0 += (c0 < k0) + (c1 < k0) + (c2 < k0) + (c3 < k0);
            r1 += (c0 < k1) + (c1 < k1) + (c2 < k1) + (c3 < k1);
            r2 += (c0 < k2) + (c1 < k2) + (c2 < k2) + (c3 < k2);
            r3 += (c0 < k3) + (c1 < k3) + (c2 < k3) + (c3 < k3);
        }
        if (r0 < TOPK) { eo[r0] = (float)(unsigned)(k0 & 0xFFFFFFFFu); dno[r0] = __uint_as_float((unsigned)(k0 >> 32)); }
        if (r1 < TOPK) { eo[r1] = (float)(unsigned)(k1 & 0xFFFFFFFFu); dno[r1] = __uint_as_float((unsigned)(k1 >> 32)); }
        if (r2 < TOPK) { eo[r2] = (float)(unsigned)(k2 & 0xFFFFFFFFu); dno[r2] = __uint_as_float((unsigned)(k2 >> 32)); }
        if (r3 < TOPK) { eo[r3] = (float)(unsigned)(k3 & 0xFFFFFFFFu); dno[r3] = __uint_as_float((unsigned)(k3 >> 32)); }
    } else {
        // ---- fallback: wave-iterative exact argmin from registers (rare) ----
        ull last = 0ULL;
        for (int k = 0; k < TOPK; ++k) {
            ull best = ~0ULL;
            #pragma unroll
            for (int t = 0; t < 32; ++t) {
                ull key = ((ull)u[t] << 32) | (unsigned)(ln + 64 * t);
                if (key > last && key < best) best = key;
            }
            #pragma unroll
            for (int off = 32; off; off >>= 1) {
                ull o = __shfl_xor(best, off);
                if (o < best) best = o;
            }
            if (ln == 0) {
                eo[k]  = (float)(unsigned)(best & 0xFFFFFFFFu);
                dno[k] = __uint_as_float((unsigned)(best >> 32));
            }
            last = best;
        }
    }
}

// ---------------------------------------------------------------------------
// K2 (v3): edge features -> 32x128 matmul (MFMA bf16) -> LayerNorm -> E.
// vs v2: grid 3840 (2 tiles/wave, more store-latency hiding); regular stores
// (drop nontemporal -- let L2 buffer write bursts like the 6.8 TB/s fill).
// ---------------------------------------------------------------------------
__global__ __launch_bounds__(256) void edge_kernel(
    const float* __restrict__ eidx, const float* __restrict__ dnb,
    const float* __restrict__ We, const float* __restrict__ be,
    const float* __restrict__ ge, const float* __restrict__ bte,
    float* __restrict__ E)
{
    const int lane = threadIdx.x & 63;
    const int c    = lane & 15;        // edge within tile / A-row (h_low)
    const int g    = lane >> 4;        // k-group
    const int wid  = (int)((blockIdx.x * blockDim.x + threadIdx.x) >> 6);
    const int nw   = (int)((gridDim.x * blockDim.x) >> 6);

    short8v W[8];
    #pragma unroll
    for (int t = 0; t < 8; ++t)
        #pragma unroll
        for (int e = 0; e < 8; ++e)
            W[t][e] = f2bf(We[(g * 8 + e) * NH + t * 16 + c]);

    float fcs[8];
    #pragma unroll
    for (int e = 0; e < 8; ++e) {
        if (g < 2) fcs[e] = expf((float)(2 * e) * -0.57564627f);  // ln(1e4)/16
        else       fcs[e] = (float)((g - 2) * 8 + e) * (20.0f / 15.0f);
    }

    const int ntiles = NB * NL * TOPK / 16;
    for (int tile = wid; tile < ntiles; tile += nw) {
        const int e0   = tile * 16;
        const int edge = e0 + c;
        const float fidx = eidx[edge];
        const float Dv   = dnb[edge];
        const int   row  = edge / TOPK;
        const float d    = fidx - (float)(row & (NL - 1));

        short8v F;
        if (g == 0) {
            #pragma unroll
            for (int e = 0; e < 8; ++e) F[e] = f2bf(cosf(d * fcs[e]));
        } else if (g == 1) {
            #pragma unroll
            for (int e = 0; e < 8; ++e) F[e] = f2bf(sinf(d * fcs[e]));
        } else {
            #pragma unroll
            for (int e = 0; e < 8; ++e) {
                float tt = (Dv - fcs[e]) * 0.8f;
                F[e] = f2bf(expf(-tt * tt));
            }
        }

        f32x4 acc[8];
        const f32x4 zero = {0.0f, 0.0f, 0.0f, 0.0f};
        #pragma unroll
        for (int t = 0; t < 8; ++t)
            acc[t] = __builtin_amdgcn_mfma_f32_16x16x32_bf16(W[t], F, zero, 0, 0, 0);

        float s = 0.0f, s2 = 0.0f;
        #pragma unroll
        for (int t = 0; t < 8; ++t) {
            const f32x4 b4 = *(const f32x4*)&be[t * 16 + g * 4];
            #pragma unroll
            for (int j = 0; j < 4; ++j) {
                float vv = acc[t][j] + b4[j];
                acc[t][j] = vv;
                s  += vv;
                s2 = fmaf(vv, vv, s2);
            }
        }
        s  += __shfl_xor(s, 16);  s  += __shfl_xor(s, 32);
        s2 += __shfl_xor(s2, 16); s2 += __shfl_xor(s2, 32);
        const float mean = s * (1.0f / 128.0f);
        const float var  = fmaxf(s2 * (1.0f / 128.0f) - mean * mean, 0.0f);
        const float inv  = rsqrtf(var + 1e-5f);

        float* const Eo = E + (size_t)edge * NH;
        #pragma unroll
        for (int t = 0; t < 8; ++t) {
            const f32x4 g4  = *(const f32x4*)&ge [t * 16 + g * 4];
            const f32x4 bt4 = *(const f32x4*)&bte[t * 16 + g * 4];
            f32x4 o;
            #pragma unroll
            for (int j = 0; j < 4; ++j)
                o[j] = (acc[t][j] - mean) * inv * g4[j] + bt4[j];
            *(f32x4*)&Eo[t * 16 + g * 4] = o;
        }
    }
}

// ---------------------------------------------------------------------------
// K3: FUSED dihedral + node matmul + LayerNorm -> V. One wave per node.
// (unchanged)
// ---------------------------------------------------------------------------
__device__ __forceinline__ void loadPt(const float* XB, int t, float v[3]) {
    int r = t / 3, a = t - 3 * r;
    const float* p = XB + ((size_t)r * 4 + a) * 3;
    v[0] = p[0]; v[1] = p[1]; v[2] = p[2];
}
__device__ __forceinline__ void unit3(float v[3]) {
    float n = sqrtf(v[0]*v[0] + v[1]*v[1] + v[2]*v[2]) + 1e-8f;
    v[0] /= n; v[1] /= n; v[2] /= n;
}
__device__ __forceinline__ void cross3(const float a[3], const float b[3], float o[3]) {
    o[0] = a[1]*b[2] - a[2]*b[1];
    o[1] = a[2]*b[0] - a[0]*b[2];
    o[2] = a[0]*b[1] - a[1]*b[0];
}

__global__ __launch_bounds__(256) void vn_kernel(
    const float* __restrict__ X, const float* __restrict__ Wn,
    const float* __restrict__ bn, const float* __restrict__ gn,
    const float* __restrict__ btn, float* __restrict__ V)
{
    const int ln   = threadIdx.x & 63;
    const int wv   = threadIdx.x >> 6;
    const int node = blockIdx.x * 4 + wv;
    const int b = node >> 11, i = node & (NL - 1);
    const float* XB = X + (size_t)b * NL * 12;

    float fc = 1.0f, fs = 0.0f;                    // pad: cos(0), sin(0)
    if (ln < 3) {
        int t = 3 * i - 1 + ln;
        float an = 0.0f;
        if (t >= 0 && t <= 3 * NL - 4) {
            float p0[3], p1[3], p2[3], p3[3];
            loadPt(XB, t, p0); loadPt(XB, t + 1, p1);
            loadPt(XB, t + 2, p2); loadPt(XB, t + 3, p3);
            float u2[3], u1[3], u0[3];
            for (int cc = 0; cc < 3; ++cc) {
                u2[cc] = p1[cc] - p0[cc];
                u1[cc] = p2[cc] - p1[cc];
                u0[cc] = p3[cc] - p2[cc];
            }
            unit3(u2); unit3(u1); unit3(u0);
            float n2[3], n1[3];
            cross3(u2, u1, n2); cross3(u1, u0, n1);
            unit3(n2); unit3(n1);
            float cosD = n2[0]*n1[0] + n2[1]*n1[1] + n2[2]*n1[2];
            cosD = fminf(fmaxf(cosD, -1.0f + 1e-7f), 1.0f - 1e-7f);
            float sg = u2[0]*n1[0] + u2[1]*n1[1] + u2[2]*n1[2];
            float sgn = (sg > 0.0f) ? 1.0f : ((sg < 0.0f) ? -1.0f : 0.0f);
            an = sgn * acosf(cosD);
        }
        fc = cosf(an); fs = sinf(an);
    }
    float f[6];
    f[0] = __shfl(fc, 0); f[1] = __shfl(fc, 1); f[2] = __shfl(fc, 2);
    f[3] = __shfl(fs, 0); f[4] = __shfl(fs, 1); f[5] = __shfl(fs, 2);

    const int h0 = ln, h1 = ln + 64;
    float a0 = bn[h0], a1 = bn[h1];
    #pragma unroll
    for (int j = 0; j < 6; ++j) {
        a0 = fmaf(f[j], Wn[j * NH + h0], a0);
        a1 = fmaf(f[j], Wn[j * NH + h1], a1);
    }
    float s  = a0 + a1;
    float s2 = fmaf(a0, a0, a1 * a1);
    #pragma unroll
    for (int off = 32; off; off >>= 1) {
        s  += __shfl_xor(s, off);
        s2 += __shfl_xor(s2, off);
    }
    float mean = s * (1.0f / 128.0f);
    float var  = fmaxf(s2 * (1.0f / 128.0f) - mean * mean, 0.0f);
    float inv  = rsqrtf(var + 1e-5f);
    float* o = V + (size_t)node * NH;
    o[h0] = (a0 - mean) * inv * gn[h0] + btn[h0];
    o[h1] = (a1 - mean) * inv * gn[h1] + btn[h1];
}

extern "C" void kernel_launch(void* const* d_in, const int* in_sizes, int n_in,
                              void* d_out, int out_size, void* d_ws, size_t ws_size,
                              hipStream_t stream)
{
    const float* X    = (const float*)d_in[0];
    const float* mask = (const float*)d_in[1];
    const float* Wn   = (const float*)d_in[2];
    const float* bn   = (const float*)d_in[3];
    const float* We   = (const float*)d_in[4];
    const float* be   = (const float*)d_in[5];
    const float* gn   = (const float*)d_in[6];
    const float* btn  = (const float*)d_in[7];
    const float* ge   = (const float*)d_in[8];
    const float* bte  = (const float*)d_in[9];

    float* out = (float*)d_out;
    float* V   = out;                                   // (8,2048,128)
    float* E   = V  + (size_t)NB * NL * NH;             // (8,2048,30,128)
    float* EI  = E  + (size_t)NB * NL * TOPK * NH;      // (8,2048,30) as float

    float4* P  = (float4*)d_ws;                         // SoA (x,y,z,m), 256 KB
    float* dnb = (float*)d_ws + 4 * (size_t)NB * NL;    // D_neighbors scratch

    hipLaunchKernelGGL(xpose_kernel, dim3((NB * NL + 255)/256), dim3(256), 0, stream,
                       X, mask, P);
    hipLaunchKernelGGL(topk_kernel,  dim3(NB * NL / 4),         dim3(256), 0, stream,
                       P, EI, dnb);
    // ATTRIBUTION PROBE: vn launched twice (pure function of X -> idempotent).
    // dur(R11) = base + T_vn; R12 drops the dup to read T_vn exactly.
    hipLaunchKernelGGL(vn_kernel,    dim3(NB * NL / 4),         dim3(256), 0, stream,
                       X, Wn, bn, gn, btn, V);
    hipLaunchKernelGGL(vn_kernel,    dim3(NB * NL / 4),         dim3(256), 0, stream,
                       X, Wn, bn, gn, btn, V);
    hipLaunchKernelGGL(edge_kernel,  dim3(3840),                dim3(256), 0, stream,
                       EI, dnb, We, be, ge, bte, E);
}

// Round 12
// 158.205 us; speedup vs baseline: 2.0029x; 1.0773x over previous
//
#include <hip/hip_runtime.h>
#include <cstdint>
#include <cstddef>

#define NB 8
#define NL 2048
#define TOPK 30
#define NH 128
#define CAND_CAP 256

typedef unsigned long long ull;
typedef __attribute__((ext_vector_type(8))) short short8v;   // 8 bf16
typedef __attribute__((ext_vector_type(4))) float f32x4;

__device__ __forceinline__ short f2bf(float f) {
    unsigned int b = __float_as_uint(f);
    b += 0x7fffu + ((b >> 16) & 1u);          // round-to-nearest-even
    return (short)(b >> 16);
}

// ---------------------------------------------------------------------------
// K0: pack CA coords + mask into SoA float4 (x,y,z,m) for coalesced loads.
// ---------------------------------------------------------------------------
__global__ __launch_bounds__(256) void xpose_kernel(
    const float* __restrict__ X, const float* __restrict__ mask,
    float4* __restrict__ P)
{
    int t = blockIdx.x * blockDim.x + threadIdx.x;
    if (t >= NB * NL) return;
    const float* p = X + (size_t)t * 12 + 3;
    P[t] = make_float4(p[0], p[1], p[2], mask[t]);
}

// ---------------------------------------------------------------------------
// K1 (FUSED topk+edge): one WAVE per row.
// Phase A = topk v7 (register-resident distances, bitonic lane-min threshold,
// ballot compaction, rank-based exact selection; key=(bits<<32)|j ==
// lax.top_k stable order). Selected keys parked in LDS sel[wv][30].
// Phase B = edge features -> MFMA 32x128 -> LayerNorm -> nontemporal E store,
// inlined per row (2 tiles: edges 0-15, 16-29). Store traffic (251 MB)
// overlaps other waves' VALU phase; eidx/dnb global round-trip eliminated.
// ---------------------------------------------------------------------------
__global__ __launch_bounds__(256) void topk_edge_kernel(
    const float4* __restrict__ P,
    const float* __restrict__ We, const float* __restrict__ be,
    const float* __restrict__ ge, const float* __restrict__ bte,
    float* __restrict__ eidx, float* __restrict__ E)
{
    __shared__ ull cand[4][CAND_CAP];              // 8 KB
    __shared__ ull sel[4][TOPK + 2];               // 1 KB

    const int tid = threadIdx.x;
    const int wv  = tid >> 6;
    const int ln  = tid & 63;
    const int row = blockIdx.x * 4 + wv;           // 4 consecutive rows/block
    const int b   = row >> 11;
    const int i   = row & (NL - 1);

    const float4* Pb = P + (size_t)b * NL;
    const float4 pi = Pb[i];
    const float xi = pi.x, yi = pi.y, zi = pi.z, mi = pi.w;

    // ---- P1: distances once; mask flag in sign bit; 4-way max chains ----
    unsigned int u[32];
    float lm0 = 0.0f, lm1 = 0.0f, lm2 = 0.0f, lm3 = 0.0f;
    #pragma unroll
    for (int t = 0; t < 32; t += 4) {
        #pragma unroll
        for (int q = 0; q < 4; ++q) {
            const float4 pj = Pb[ln + 64 * (t + q)];
            float dx = xi - pj.x;
            float dy = yi - pj.y;
            float dz = zi - pj.z;
            float s = __fadd_rn(__fmul_rn(dx, dx), __fmul_rn(dy, dy));
            s = __fadd_rn(s, __fmul_rn(dz, dz));
            s = __fadd_rn(s, 1e-6f);
            float m2 = __fmul_rn(pj.w, mi);        // binary mask: 0 or 1
            float d  = __fmul_rn(m2, __fsqrt_rn(s));
            u[t + q] = __float_as_uint(d) | ((m2 == 0.0f) ? 0x80000000u : 0u);
            if      (q == 0) lm0 = fmaxf(lm0, d);
            else if (q == 1) lm1 = fmaxf(lm1, d);
            else if (q == 2) lm2 = fmaxf(lm2, d);
            else             lm3 = fmaxf(lm3, d);
        }
    }
    float lmax = fmaxf(fmaxf(lm0, lm1), fmaxf(lm2, lm3));
    #pragma unroll
    for (int off = 32; off; off >>= 1) lmax = fmaxf(lmax, __shfl_xor(lmax, off));
    const unsigned int DMB = __float_as_uint(__fadd_rn(lmax, 1.0f));

    // ---- P2: adjusted bits via select + per-lane min (4-way chains) ----
    unsigned int um0 = 0xFFFFFFFFu, um1 = 0xFFFFFFFFu,
                 um2 = 0xFFFFFFFFu, um3 = 0xFFFFFFFFu;
    #pragma unroll
    for (int t = 0; t < 32; t += 4) {
        unsigned int b0 = (u[t+0] & 0x80000000u) ? DMB : u[t+0];
        unsigned int b1 = (u[t+1] & 0x80000000u) ? DMB : u[t+1];
        unsigned int b2 = (u[t+2] & 0x80000000u) ? DMB : u[t+2];
        unsigned int b3 = (u[t+3] & 0x80000000u) ? DMB : u[t+3];
        u[t+0] = b0; u[t+1] = b1; u[t+2] = b2; u[t+3] = b3;
        um0 = min(um0, b0); um1 = min(um1, b1);
        um2 = min(um2, b2); um3 = min(um3, b3);
    }
    unsigned int umin = min(min(um0, um1), min(um2, um3));

    // ---- P3: bitonic sort of 64 lane-minima -> threshold T at rank 29 ----
    unsigned int v = umin;
    #pragma unroll
    for (int k = 2; k <= 64; k <<= 1) {
        #pragma unroll
        for (int j = k >> 1; j > 0; j >>= 1) {
            unsigned int o = __shfl_xor(v, j);
            bool asc   = ((ln & k) == 0);
            bool lower = ((ln & j) == 0);
            v = (lower == asc) ? min(v, o) : max(v, o);
        }
    }
    const unsigned int T = __shfl(v, TOPK - 1);

    // ---- P4: ordered ballot compaction ----
    unsigned int base = 0;
    #pragma unroll
    for (int t = 0; t < 32; ++t) {
        bool act = u[t] <= T;
        ull m = __ballot(act);
        if (act) {
            unsigned int pos = base + (unsigned)__popcll(m & ((1ull << ln) - 1ull));
            if (pos < CAND_CAP)
                cand[wv][pos] = ((ull)u[t] << 32) | (unsigned)(ln + 64 * t);
        }
        base += (unsigned)__popcll(m);
    }
    const unsigned int cnt = base;

    float* eo = eidx + (size_t)row * TOPK;

    if (cnt <= CAND_CAP) {
        // ---- P5: rank-based exact selection, unrolled x4 ----
        ull k0 = ((unsigned)ln        < cnt) ? cand[wv][ln]        : ~0ULL;
        ull k1 = ((unsigned)ln +  64u < cnt) ? cand[wv][ln +  64]  : ~0ULL;
        ull k2 = ((unsigned)ln + 128u < cnt) ? cand[wv][ln + 128]  : ~0ULL;
        ull k3 = ((unsigned)ln + 192u < cnt) ? cand[wv][ln + 192]  : ~0ULL;
        int r0 = 0, r1 = 0, r2 = 0, r3 = 0;
        for (unsigned int p = 0; p < cnt; p += 4) {
            ull c0 = cand[wv][p];
            ull c1 = (p + 1 < cnt) ? cand[wv][p + 1] : ~0ULL;
            ull c2 = (p + 2 < cnt) ? cand[wv][p + 2] : ~0ULL;
            ull c3 = (p + 3 < cnt) ? cand[wv][p + 3] : ~0ULL;
            r0 += (c0 < k0) + (c1 < k0) + (c2 < k0) + (c3 < k0);
            r1 += (c0 < k1) + (c1 < k1) + (c2 < k1) + (c3 < k1);
            r2 += (c0 < k2) + (c1 < k2) + (c2 < k2) + (c3 < k2);
            r3 += (c0 < k3) + (c1 < k3) + (c2 < k3) + (c3 < k3);
        }
        if (r0 < TOPK) { eo[r0] = (float)(unsigned)(k0 & 0xFFFFFFFFu); sel[wv][r0] = k0; }
        if (r1 < TOPK) { eo[r1] = (float)(unsigned)(k1 & 0xFFFFFFFFu); sel[wv][r1] = k1; }
        if (r2 < TOPK) { eo[r2] = (float)(unsigned)(k2 & 0xFFFFFFFFu); sel[wv][r2] = k2; }
        if (r3 < TOPK) { eo[r3] = (float)(unsigned)(k3 & 0xFFFFFFFFu); sel[wv][r3] = k3; }
    } else {
        // ---- fallback: wave-iterative exact argmin from registers (rare) ----
        ull last = 0ULL;
        for (int k = 0; k < TOPK; ++k) {
            ull best = ~0ULL;
            #pragma unroll
            for (int t = 0; t < 32; ++t) {
                ull key = ((ull)u[t] << 32) | (unsigned)(ln + 64 * t);
                if (key > last && key < best) best = key;
            }
            #pragma unroll
            for (int off = 32; off; off >>= 1) {
                ull o = __shfl_xor(best, off);
                if (o < best) best = o;
            }
            if (ln == 0) {
                eo[k]  = (float)(unsigned)(best & 0xFFFFFFFFu);
                sel[wv][k] = best;
            }
            last = best;
        }
    }

    // keep phase-B loads from being hoisted into phase A (register pressure)
    __builtin_amdgcn_sched_barrier(0);

    // =========================== Phase B: edge ============================
    const int c = ln & 15;             // edge within tile / D col
    const int g = ln >> 4;             // k-group / D row block

    short8v W[8];
    #pragma unroll
    for (int t = 0; t < 8; ++t)
        #pragma unroll
        for (int e = 0; e < 8; ++e)
            W[t][e] = f2bf(We[(g * 8 + e) * NH + t * 16 + c]);

    float fcs[8];
    #pragma unroll
    for (int e = 0; e < 8; ++e) {
        if (g < 2) fcs[e] = expf((float)(2 * e) * -0.57564627f);  // ln(1e4)/16
        else       fcs[e] = (float)((g - 2) * 8 + e) * (20.0f / 15.0f);
    }

    const float fi = (float)i;
    float* const Erow = E + (size_t)row * TOPK * NH;

    #pragma unroll
    for (int tile = 0; tile < 2; ++tile) {
        const int k = (tile == 0) ? c : 16 + ((c < 14) ? c : 13);  // dup pad
        const ull  skey = sel[wv][k];
        const float fidx = (float)(unsigned)(skey & 0xFFFFFFFFu);
        const float Dv   = __uint_as_float((unsigned)(skey >> 32));
        const float d    = fidx - fi;

        short8v F;
        if (g == 0) {
            #pragma unroll
            for (int e = 0; e < 8; ++e) F[e] = f2bf(cosf(d * fcs[e]));
        } else if (g == 1) {
            #pragma unroll
            for (int e = 0; e < 8; ++e) F[e] = f2bf(sinf(d * fcs[e]));
        } else {
            #pragma unroll
            for (int e = 0; e < 8; ++e) {
                float tt = (Dv - fcs[e]) * 0.8f;
                F[e] = f2bf(expf(-tt * tt));
            }
        }

        f32x4 acc[8];
        const f32x4 zero = {0.0f, 0.0f, 0.0f, 0.0f};
        #pragma unroll
        for (int t = 0; t < 8; ++t)
            acc[t] = __builtin_amdgcn_mfma_f32_16x16x32_bf16(W[t], F, zero, 0, 0, 0);

        float s = 0.0f, s2 = 0.0f;
        #pragma unroll
        for (int t = 0; t < 8; ++t) {
            const f32x4 b4 = *(const f32x4*)&be[t * 16 + g * 4];
            #pragma unroll
            for (int j = 0; j < 4; ++j) {
                float vv = acc[t][j] + b4[j];
                acc[t][j] = vv;
                s  += vv;
                s2 = fmaf(vv, vv, s2);
            }
        }
        s  += __shfl_xor(s, 16);  s  += __shfl_xor(s, 32);
        s2 += __shfl_xor(s2, 16); s2 += __shfl_xor(s2, 32);
        const float mean = s * (1.0f / 128.0f);
        const float var  = fmaxf(s2 * (1.0f / 128.0f) - mean * mean, 0.0f);
        const float inv  = rsqrtf(var + 1e-5f);

        if (tile == 0 || c < 14) {
            float* const Eo = Erow + (size_t)k * NH;
            #pragma unroll
            for (int t = 0; t < 8; ++t) {
                const f32x4 g4  = *(const f32x4*)&ge [t * 16 + g * 4];
                const f32x4 bt4 = *(const f32x4*)&bte[t * 16 + g * 4];
                f32x4 o;
                #pragma unroll
                for (int j = 0; j < 4; ++j)
                    o[j] = (acc[t][j] - mean) * inv * g4[j] + bt4[j];
                __builtin_nontemporal_store(o, (f32x4*)&Eo[t * 16 + g * 4]);
            }
        }
    }
}

// ---------------------------------------------------------------------------
// K3: FUSED dihedral + node matmul + LayerNorm -> V. One wave per node.
// (unchanged)
// ---------------------------------------------------------------------------
__device__ __forceinline__ void loadPt(const float* XB, int t, float v[3]) {
    int r = t / 3, a = t - 3 * r;
    const float* p = XB + ((size_t)r * 4 + a) * 3;
    v[0] = p[0]; v[1] = p[1]; v[2] = p[2];
}
__device__ __forceinline__ void unit3(float v[3]) {
    float n = sqrtf(v[0]*v[0] + v[1]*v[1] + v[2]*v[2]) + 1e-8f;
    v[0] /= n; v[1] /= n; v[2] /= n;
}
__device__ __forceinline__ void cross3(const float a[3], const float b[3], float o[3]) {
    o[0] = a[1]*b[2] - a[2]*b[1];
    o[1] = a[2]*b[0] - a[0]*b[2];
    o[2] = a[0]*b[1] - a[1]*b[0];
}

__global__ __launch_bounds__(256) void vn_kernel(
    const float* __restrict__ X, const float* __restrict__ Wn,
    const float* __restrict__ bn, const float* __restrict__ gn,
    const float* __restrict__ btn, float* __restrict__ V)
{
    const int ln   = threadIdx.x & 63;
    const int wv   = threadIdx.x >> 6;
    const int node = blockIdx.x * 4 + wv;
    const int b = node >> 11, i = node & (NL - 1);
    const float* XB = X + (size_t)b * NL * 12;

    float fc = 1.0f, fs = 0.0f;                    // pad: cos(0), sin(0)
    if (ln < 3) {
        int t = 3 * i - 1 + ln;
        float an = 0.0f;
        if (t >= 0 && t <= 3 * NL - 4) {
            float p0[3], p1[3], p2[3], p3[3];
            loadPt(XB, t, p0); loadPt(XB, t + 1, p1);
            loadPt(XB, t + 2, p2); loadPt(XB, t + 3, p3);
            float u2[3], u1[3], u0[3];
            for (int cc = 0; cc < 3; ++cc) {
                u2[cc] = p1[cc] - p0[cc];
                u1[cc] = p2[cc] - p1[cc];
                u0[cc] = p3[cc] - p2[cc];
            }
            unit3(u2); unit3(u1); unit3(u0);
            float n2[3], n1[3];
            cross3(u2, u1, n2); cross3(u1, u0, n1);
            unit3(n2); unit3(n1);
            float cosD = n2[0]*n1[0] + n2[1]*n1[1] + n2[2]*n1[2];
            cosD = fminf(fmaxf(cosD, -1.0f + 1e-7f), 1.0f - 1e-7f);
            float sg = u2[0]*n1[0] + u2[1]*n1[1] + u2[2]*n1[2];
            float sgn = (sg > 0.0f) ? 1.0f : ((sg < 0.0f) ? -1.0f : 0.0f);
            an = sgn * acosf(cosD);
        }
        fc = cosf(an); fs = sinf(an);
    }
    float f[6];
    f[0] = __shfl(fc, 0); f[1] = __shfl(fc, 1); f[2] = __shfl(fc, 2);
    f[3] = __shfl(fs, 0); f[4] = __shfl(fs, 1); f[5] = __shfl(fs, 2);

    const int h0 = ln, h1 = ln + 64;
    float a0 = bn[h0], a1 = bn[h1];
    #pragma unroll
    for (int j = 0; j < 6; ++j) {
        a0 = fmaf(f[j], Wn[j * NH + h0], a0);
        a1 = fmaf(f[j], Wn[j * NH + h1], a1);
    }
    float s  = a0 + a1;
    float s2 = fmaf(a0, a0, a1 * a1);
    #pragma unroll
    for (int off = 32; off; off >>= 1) {
        s  += __shfl_xor(s, off);
        s2 += __shfl_xor(s2, off);
    }
    float mean = s * (1.0f / 128.0f);
    float var  = fmaxf(s2 * (1.0f / 128.0f) - mean * mean, 0.0f);
    float inv  = rsqrtf(var + 1e-5f);
    float* o = V + (size_t)node * NH;
    o[h0] = (a0 - mean) * inv * gn[h0] + btn[h0];
    o[h1] = (a1 - mean) * inv * gn[h1] + btn[h1];
}

extern "C" void kernel_launch(void* const* d_in, const int* in_sizes, int n_in,
                              void* d_out, int out_size, void* d_ws, size_t ws_size,
                              hipStream_t stream)
{
    const float* X    = (const float*)d_in[0];
    const float* mask = (const float*)d_in[1];
    const float* Wn   = (const float*)d_in[2];
    const float* bn   = (const float*)d_in[3];
    const float* We   = (const float*)d_in[4];
    const float* be   = (const float*)d_in[5];
    const float* gn   = (const float*)d_in[6];
    const float* btn  = (const float*)d_in[7];
    const float* ge   = (const float*)d_in[8];
    const float* bte  = (const float*)d_in[9];

    float* out = (float*)d_out;
    float* V   = out;                                   // (8,2048,128)
    float* E   = V  + (size_t)NB * NL * NH;             // (8,2048,30,128)
    float* EI  = E  + (size_t)NB * NL * TOPK * NH;      // (8,2048,30) as float

    float4* P  = (float4*)d_ws;                         // SoA (x,y,z,m), 256 KB

    hipLaunchKernelGGL(xpose_kernel,     dim3((NB * NL + 255)/256), dim3(256), 0, stream,
                       X, mask, P);
    hipLaunchKernelGGL(topk_edge_kernel, dim3(NB * NL / 4),         dim3(256), 0, stream,
                       P, We, be, ge, bte, EI, E);
    hipLaunchKernelGGL(vn_kernel,        dim3(NB * NL / 4),         dim3(256), 0, stream,
                       X, Wn, bn, gn, btn, V);
}

// Round 13
// 145.497 us; speedup vs baseline: 2.1778x; 1.0873x over previous
//
#include <hip/hip_runtime.h>
#include <cstdint>
#include <cstddef>

#define NB 8
#define NL 2048
#define TOPK 30
#define NH 128
#define CAND_CAP 256

typedef unsigned long long ull;
typedef __attribute__((ext_vector_type(8))) short short8v;   // 8 bf16
typedef __attribute__((ext_vector_type(4))) float f32x4;

__device__ __forceinline__ short f2bf(float f) {
    unsigned int b = __float_as_uint(f);
    b += 0x7fffu + ((b >> 16) & 1u);          // round-to-nearest-even
    return (short)(b >> 16);
}

// ---------------------------------------------------------------------------
// K0: pack CA coords + mask into SoA float4 (x,y,z,m) for coalesced loads.
// ---------------------------------------------------------------------------
__global__ __launch_bounds__(256) void xpose_kernel(
    const float* __restrict__ X, const float* __restrict__ mask,
    float4* __restrict__ P)
{
    int t = blockIdx.x * blockDim.x + threadIdx.x;
    if (t >= NB * NL) return;
    const float* p = X + (size_t)t * 12 + 3;
    P[t] = make_float4(p[0], p[1], p[2], mask[t]);
}

// ---------------------------------------------------------------------------
// K1 (v7, identical to R11 -- proven ~44 us): one WAVE per row,
// register-resident distances, bitonic lane-min threshold, ballot compaction,
// rank-based exact selection. key=(bits<<32)|j == lax.top_k stable order.
// ---------------------------------------------------------------------------
__global__ __launch_bounds__(256) void topk_kernel(
    const float4* __restrict__ P,
    float* __restrict__ eidx, float* __restrict__ dnb)
{
    __shared__ ull cand[4][CAND_CAP];              // 8 KB

    const int tid = threadIdx.x;
    const int wv  = tid >> 6;
    const int ln  = tid & 63;
    const int row = blockIdx.x * 4 + wv;
    const int b   = row >> 11;
    const int i   = row & (NL - 1);

    const float4* Pb = P + (size_t)b * NL;
    const float4 pi = Pb[i];
    const float xi = pi.x, yi = pi.y, zi = pi.z, mi = pi.w;

    unsigned int u[32];
    float lm0 = 0.0f, lm1 = 0.0f, lm2 = 0.0f, lm3 = 0.0f;
    #pragma unroll
    for (int t = 0; t < 32; t += 4) {
        #pragma unroll
        for (int q = 0; q < 4; ++q) {
            const float4 pj = Pb[ln + 64 * (t + q)];
            float dx = xi - pj.x;
            float dy = yi - pj.y;
            float dz = zi - pj.z;
            float s = __fadd_rn(__fmul_rn(dx, dx), __fmul_rn(dy, dy));
            s = __fadd_rn(s, __fmul_rn(dz, dz));
            s = __fadd_rn(s, 1e-6f);
            float m2 = __fmul_rn(pj.w, mi);
            float d  = __fmul_rn(m2, __fsqrt_rn(s));
            u[t + q] = __float_as_uint(d) | ((m2 == 0.0f) ? 0x80000000u : 0u);
            if      (q == 0) lm0 = fmaxf(lm0, d);
            else if (q == 1) lm1 = fmaxf(lm1, d);
            else if (q == 2) lm2 = fmaxf(lm2, d);
            else             lm3 = fmaxf(lm3, d);
        }
    }
    float lmax = fmaxf(fmaxf(lm0, lm1), fmaxf(lm2, lm3));
    #pragma unroll
    for (int off = 32; off; off >>= 1) lmax = fmaxf(lmax, __shfl_xor(lmax, off));
    const unsigned int DMB = __float_as_uint(__fadd_rn(lmax, 1.0f));

    unsigned int um0 = 0xFFFFFFFFu, um1 = 0xFFFFFFFFu,
                 um2 = 0xFFFFFFFFu, um3 = 0xFFFFFFFFu;
    #pragma unroll
    for (int t = 0; t < 32; t += 4) {
        unsigned int b0 = (u[t+0] & 0x80000000u) ? DMB : u[t+0];
        unsigned int b1 = (u[t+1] & 0x80000000u) ? DMB : u[t+1];
        unsigned int b2 = (u[t+2] & 0x80000000u) ? DMB : u[t+2];
        unsigned int b3 = (u[t+3] & 0x80000000u) ? DMB : u[t+3];
        u[t+0] = b0; u[t+1] = b1; u[t+2] = b2; u[t+3] = b3;
        um0 = min(um0, b0); um1 = min(um1, b1);
        um2 = min(um2, b2); um3 = min(um3, b3);
    }
    unsigned int umin = min(min(um0, um1), min(um2, um3));

    unsigned int v = umin;
    #pragma unroll
    for (int k = 2; k <= 64; k <<= 1) {
        #pragma unroll
        for (int j = k >> 1; j > 0; j >>= 1) {
            unsigned int o = __shfl_xor(v, j);
            bool asc   = ((ln & k) == 0);
            bool lower = ((ln & j) == 0);
            v = (lower == asc) ? min(v, o) : max(v, o);
        }
    }
    const unsigned int T = __shfl(v, TOPK - 1);

    unsigned int base = 0;
    #pragma unroll
    for (int t = 0; t < 32; ++t) {
        bool act = u[t] <= T;
        ull m = __ballot(act);
        if (act) {
            unsigned int pos = base + (unsigned)__popcll(m & ((1ull << ln) - 1ull));
            if (pos < CAND_CAP)
                cand[wv][pos] = ((ull)u[t] << 32) | (unsigned)(ln + 64 * t);
        }
        base += (unsigned)__popcll(m);
    }
    const unsigned int cnt = base;

    float* eo  = eidx + (size_t)row * TOPK;
    float* dno = dnb  + (size_t)row * TOPK;

    if (cnt <= CAND_CAP) {
        ull k0 = ((unsigned)ln        < cnt) ? cand[wv][ln]        : ~0ULL;
        ull k1 = ((unsigned)ln +  64u < cnt) ? cand[wv][ln +  64]  : ~0ULL;
        ull k2 = ((unsigned)ln + 128u < cnt) ? cand[wv][ln + 128]  : ~0ULL;
        ull k3 = ((unsigned)ln + 192u < cnt) ? cand[wv][ln + 192]  : ~0ULL;
        int r0 = 0, r1 = 0, r2 = 0, r3 = 0;
        for (unsigned int p = 0; p < cnt; p += 4) {
            ull c0 = cand[wv][p];
            ull c1 = (p + 1 < cnt) ? cand[wv][p + 1] : ~0ULL;
            ull c2 = (p + 2 < cnt) ? cand[wv][p + 2] : ~0ULL;
            ull c3 = (p + 3 < cnt) ? cand[wv][p + 3] : ~0ULL;
            r0 += (c0 < k0) + (c1 < k0) + (c2 < k0) + (c3 < k0);
            r1 += (c0 < k1) + (c1 < k1) + (c2 < k1) + (c3 < k1);
            r2 += (c0 < k2) + (c1 < k2) + (c2 < k2) + (c3 < k2);
            r3 += (c0 < k3) + (c1 < k3) + (c2 < k3) + (c3 < k3);
        }
        if (r0 < TOPK) { eo[r0] = (float)(unsigned)(k0 & 0xFFFFFFFFu); dno[r0] = __uint_as_float((unsigned)(k0 >> 32)); }
        if (r1 < TOPK) { eo[r1] = (float)(unsigned)(k1 & 0xFFFFFFFFu); dno[r1] = __uint_as_float((unsigned)(k1 >> 32)); }
        if (r2 < TOPK) { eo[r2] = (float)(unsigned)(k2 & 0xFFFFFFFFu); dno[r2] = __uint_as_float((unsigned)(k2 >> 32)); }
        if (r3 < TOPK) { eo[r3] = (float)(unsigned)(k3 & 0xFFFFFFFFu); dno[r3] = __uint_as_float((unsigned)(k3 >> 32)); }
    } else {
        ull last = 0ULL;
        for (int k = 0; k < TOPK; ++k) {
            ull best = ~0ULL;
            #pragma unroll
            for (int t = 0; t < 32; ++t) {
                ull key = ((ull)u[t] << 32) | (unsigned)(ln + 64 * t);
                if (key > last && key < best) best = key;
            }
            #pragma unroll
            for (int off = 32; off; off >>= 1) {
                ull o = __shfl_xor(best, off);
                if (o < best) best = o;
            }
            if (ln == 0) {
                eo[k]  = (float)(unsigned)(best & 0xFFFFFFFFu);
                dno[k] = __uint_as_float((unsigned)(best >> 32));
            }
            last = best;
        }
    }
}

// ---------------------------------------------------------------------------
// K2 (v2, identical to R8/R9 -- measured ~49 us): edge features -> MFMA
// 32x128 -> LayerNorm -> nontemporal E. Lane owns one edge; dwordx4 stores.
// ---------------------------------------------------------------------------
__global__ __launch_bounds__(256) void edge_kernel(
    const float* __restrict__ eidx, const float* __restrict__ dnb,
    const float* __restrict__ We, const float* __restrict__ be,
    const float* __restrict__ ge, const float* __restrict__ bte,
    float* __restrict__ E)
{
    const int lane = threadIdx.x & 63;
    const int c    = lane & 15;
    const int g    = lane >> 4;
    const int wid  = (int)((blockIdx.x * blockDim.x + threadIdx.x) >> 6);
    const int nw   = (int)((gridDim.x * blockDim.x) >> 6);

    short8v W[8];
    #pragma unroll
    for (int t = 0; t < 8; ++t)
        #pragma unroll
        for (int e = 0; e < 8; ++e)
            W[t][e] = f2bf(We[(g * 8 + e) * NH + t * 16 + c]);

    float fcs[8];
    #pragma unroll
    for (int e = 0; e < 8; ++e) {
        if (g < 2) fcs[e] = expf((float)(2 * e) * -0.57564627f);  // ln(1e4)/16
        else       fcs[e] = (float)((g - 2) * 8 + e) * (20.0f / 15.0f);
    }

    const int ntiles = NB * NL * TOPK / 16;
    for (int tile = wid; tile < ntiles; tile += nw) {
        const int e0   = tile * 16;
        const int edge = e0 + c;
        const float fidx = eidx[edge];
        const float Dv   = dnb[edge];
        const int   row  = edge / TOPK;
        const float d    = fidx - (float)(row & (NL - 1));

        short8v F;
        if (g == 0) {
            #pragma unroll
            for (int e = 0; e < 8; ++e) F[e] = f2bf(cosf(d * fcs[e]));
        } else if (g == 1) {
            #pragma unroll
            for (int e = 0; e < 8; ++e) F[e] = f2bf(sinf(d * fcs[e]));
        } else {
            #pragma unroll
            for (int e = 0; e < 8; ++e) {
                float tt = (Dv - fcs[e]) * 0.8f;
                F[e] = f2bf(expf(-tt * tt));
            }
        }

        f32x4 acc[8];
        const f32x4 zero = {0.0f, 0.0f, 0.0f, 0.0f};
        #pragma unroll
        for (int t = 0; t < 8; ++t)
            acc[t] = __builtin_amdgcn_mfma_f32_16x16x32_bf16(W[t], F, zero, 0, 0, 0);

        float s = 0.0f, s2 = 0.0f;
        #pragma unroll
        for (int t = 0; t < 8; ++t) {
            const f32x4 b4 = *(const f32x4*)&be[t * 16 + g * 4];
            #pragma unroll
            for (int j = 0; j < 4; ++j) {
                float vv = acc[t][j] + b4[j];
                acc[t][j] = vv;
                s  += vv;
                s2 = fmaf(vv, vv, s2);
            }
        }
        s  += __shfl_xor(s, 16);  s  += __shfl_xor(s, 32);
        s2 += __shfl_xor(s2, 16); s2 += __shfl_xor(s2, 32);
        const float mean = s * (1.0f / 128.0f);
        const float var  = fmaxf(s2 * (1.0f / 128.0f) - mean * mean, 0.0f);
        const float inv  = rsqrtf(var + 1e-5f);

        float* const Eo = E + (size_t)edge * NH;
        #pragma unroll
        for (int t = 0; t < 8; ++t) {
            const f32x4 g4  = *(const f32x4*)&ge [t * 16 + g * 4];
            const f32x4 bt4 = *(const f32x4*)&bte[t * 16 + g * 4];
            f32x4 o;
            #pragma unroll
            for (int j = 0; j < 4; ++j)
                o[j] = (acc[t][j] - mean) * inv * g4[j] + bt4[j];
            __builtin_nontemporal_store(o, (f32x4*)&Eo[t * 16 + g * 4]);
        }
    }
}

// ---------------------------------------------------------------------------
// K3 (v2): vn with NODE-PER-LANE dihedrals (all 64 lanes busy) and
// shuffle-free LayerNorm via a per-wave precomputed quadratic form:
//   mean = (f . csW + sum_b)/128
//   E[x2] = (f^T M f + 2 f.Wb + sum_b2)/128,  M_jk = sum_h W_jh W_kh
// Phase 0: each wave reduces M (21 sym), Wb(6), csW(6), sum_b, sum_b2 from
// its own w0/w1 registers (~210 shuffles, amortized over 64 nodes).
// Phase 1: lane = node: 6 backbone points (static row/atom map, clamped),
// 5 unit vecs, 4 normals, 3 angles (validity: a0: i>=1; a1,a2: i<=2046),
// f[6], mean, inv -> wave-local LDS (no barrier needed).
// Phase 2: cooperative coalesced stores: lane ln writes h=ln and h=ln+64.
// ---------------------------------------------------------------------------
__global__ __launch_bounds__(256) void vn_kernel(
    const float* __restrict__ X, const float* __restrict__ Wn,
    const float* __restrict__ bn, const float* __restrict__ gn,
    const float* __restrict__ btn, float* __restrict__ V)
{
    __shared__ float fsh[4][64][8];                 // 8 KB

    const int tid = threadIdx.x;
    const int wv  = tid >> 6;
    const int ln  = tid & 63;
    const int node = blockIdx.x * 256 + tid;        // grid = 64 blocks
    const int b = node >> 11, i = node & (NL - 1);

    // ---- weights for this lane's two h-columns (used in phases 0 and 2) ----
    const int h0 = ln, h1 = ln + 64;
    float w0[6], w1[6];
    #pragma unroll
    for (int j = 0; j < 6; ++j) { w0[j] = Wn[j * NH + h0]; w1[j] = Wn[j * NH + h1]; }
    const float bb0 = bn[h0], bb1 = bn[h1];
    const float g0  = gn[h0], g1  = gn[h1];
    const float t0  = btn[h0], t1 = btn[h1];

    // ---- Phase 0: wave-reduce LN stats (35 values) ----
    float st[35];
    {
        int idx = 0;
        #pragma unroll
        for (int j = 0; j < 6; ++j)
            #pragma unroll
            for (int k = j; k < 6; ++k)
                st[idx++] = w0[j] * w0[k] + w1[j] * w1[k];     // M upper-tri
        #pragma unroll
        for (int j = 0; j < 6; ++j) st[21 + j] = w0[j] * bb0 + w1[j] * bb1; // Wb
        #pragma unroll
        for (int j = 0; j < 6; ++j) st[27 + j] = w0[j] + w1[j];             // csW
        st[33] = bb0 + bb1;
        st[34] = bb0 * bb0 + bb1 * bb1;
        #pragma unroll
        for (int q = 0; q < 35; ++q) {
            float vv = st[q];
            #pragma unroll
            for (int off = 32; off; off >>= 1) vv += __shfl_xor(vv, off);
            st[q] = vv;
        }
    }

    // ---- Phase 1: dihedral features for THIS lane's node ----
    const float* XB = X + (size_t)b * NL * 12;
    // backbone points t = 3i-1 .. 3i+4: (row, atom) pairs, rows clamped
    const int rm1 = (i >= 1) ? i - 1 : 0;
    const int rp1 = (i <= NL - 2) ? i + 1 : NL - 1;
    float p[6][3];
    {
        const int rows[6]  = { rm1, i, i, i, rp1, rp1 };
        const int atoms[6] = { 2,   0, 1, 2, 0,   1   };
        #pragma unroll
        for (int k = 0; k < 6; ++k) {
            const float* q = XB + ((size_t)rows[k] * 4 + atoms[k]) * 3;
            p[k][0] = q[0]; p[k][1] = q[1]; p[k][2] = q[2];
        }
    }
    float uv[5][3], nv[4][3];
    #pragma unroll
    for (int k = 0; k < 5; ++k) {
        float vx = p[k+1][0] - p[k][0];
        float vy = p[k+1][1] - p[k][1];
        float vz = p[k+1][2] - p[k][2];
        float n = sqrtf(vx*vx + vy*vy + vz*vz) + 1e-8f;
        uv[k][0] = vx / n; uv[k][1] = vy / n; uv[k][2] = vz / n;
    }
    #pragma unroll
    for (int k = 0; k < 4; ++k) {
        float cx = uv[k][1]*uv[k+1][2] - uv[k][2]*uv[k+1][1];
        float cy = uv[k][2]*uv[k+1][0] - uv[k][0]*uv[k+1][2];
        float cz = uv[k][0]*uv[k+1][1] - uv[k][1]*uv[k+1][0];
        float n = sqrtf(cx*cx + cy*cy + cz*cz) + 1e-8f;
        nv[k][0] = cx / n; nv[k][1] = cy / n; nv[k][2] = cz / n;
    }
    float f[6];
    #pragma unroll
    for (int a = 0; a < 3; ++a) {
        bool valid = (a == 0) ? (i >= 1) : (i <= NL - 2);
        float cosD = nv[a][0]*nv[a+1][0] + nv[a][1]*nv[a+1][1] + nv[a][2]*nv[a+1][2];
        cosD = fminf(fmaxf(cosD, -1.0f + 1e-7f), 1.0f - 1e-7f);
        float sg = uv[a][0]*nv[a+1][0] + uv[a][1]*nv[a+1][1] + uv[a][2]*nv[a+1][2];
        float sgn = (sg > 0.0f) ? 1.0f : ((sg < 0.0f) ? -1.0f : 0.0f);
        float an = valid ? (sgn * acosf(cosD)) : 0.0f;
        f[a]     = cosf(an);
        f[3 + a] = sinf(an);
    }

    // in-lane mean/inv via quadratic form
    float s1 = st[33];
    #pragma unroll
    for (int j = 0; j < 6; ++j) s1 = fmaf(f[j], st[27 + j], s1);
    float qd = st[34];
    #pragma unroll
    for (int j = 0; j < 6; ++j) qd = fmaf(2.0f * f[j], st[21 + j], qd);
    {
        int idx = 0;
        #pragma unroll
        for (int j = 0; j < 6; ++j)
            #pragma unroll
            for (int k = j; k < 6; ++k) {
                float coef = (j == k) ? 1.0f : 2.0f;
                qd = fmaf(coef * f[j] * f[k], st[idx], qd);
                ++idx;
            }
    }
    const float mean = s1 * (1.0f / 128.0f);
    const float var  = fmaxf(qd * (1.0f / 128.0f) - mean * mean, 0.0f);
    const float inv  = rsqrtf(var + 1e-5f);

    #pragma unroll
    for (int j = 0; j < 6; ++j) fsh[wv][ln][j] = f[j];
    fsh[wv][ln][6] = mean;
    fsh[wv][ln][7] = inv;
    // wave-local LDS: same wave writes then reads -- lgkmcnt ordering suffices

    // ---- Phase 2: cooperative outputs, coalesced stores ----
    const int node_base = blockIdx.x * 256 + wv * 64;
    for (int nn = 0; nn < 64; ++nn) {
        const float* fr = fsh[wv][nn];
        float a0 = bb0, a1 = bb1;
        #pragma unroll
        for (int j = 0; j < 6; ++j) {
            a0 = fmaf(fr[j], w0[j], a0);
            a1 = fmaf(fr[j], w1[j], a1);
        }
        const float mn = fr[6], iv = fr[7];
        float* o = V + (size_t)(node_base + nn) * NH;
        o[h0] = (a0 - mn) * iv * g0 + t0;
        o[h1] = (a1 - mn) * iv * g1 + t1;
    }
}

extern "C" void kernel_launch(void* const* d_in, const int* in_sizes, int n_in,
                              void* d_out, int out_size, void* d_ws, size_t ws_size,
                              hipStream_t stream)
{
    const float* X    = (const float*)d_in[0];
    const float* mask = (const float*)d_in[1];
    const float* Wn   = (const float*)d_in[2];
    const float* bn   = (const float*)d_in[3];
    const float* We   = (const float*)d_in[4];
    const float* be   = (const float*)d_in[5];
    const float* gn   = (const float*)d_in[6];
    const float* btn  = (const float*)d_in[7];
    const float* ge   = (const float*)d_in[8];
    const float* bte  = (const float*)d_in[9];

    float* out = (float*)d_out;
    float* V   = out;                                   // (8,2048,128)
    float* E   = V  + (size_t)NB * NL * NH;             // (8,2048,30,128)
    float* EI  = E  + (size_t)NB * NL * TOPK * NH;      // (8,2048,30) as float

    float4* P  = (float4*)d_ws;                         // SoA (x,y,z,m), 256 KB
    float* dnb = (float*)d_ws + 4 * (size_t)NB * NL;    // D_neighbors scratch

    hipLaunchKernelGGL(xpose_kernel, dim3((NB * NL + 255)/256), dim3(256), 0, stream,
                       X, mask, P);
    hipLaunchKernelGGL(topk_kernel,  dim3(NB * NL / 4),         dim3(256), 0, stream,
                       P, EI, dnb);
    hipLaunchKernelGGL(vn_kernel,    dim3(NB * NL / 256),       dim3(256), 0, stream,
                       X, Wn, bn, gn, btn, V);
    hipLaunchKernelGGL(edge_kernel,  dim3(1920),                dim3(256), 0, stream,
                       EI, dnb, We, be, ge, bte, E);
}

// Round 14
// 140.019 us; speedup vs baseline: 2.2630x; 1.0391x over previous
//
#include <hip/hip_runtime.h>
#include <cstdint>
#include <cstddef>

#define NB 8
#define NL 2048
#define TOPK 30
#define NH 128
#define CAND_CAP 256

typedef unsigned long long ull;
typedef __attribute__((ext_vector_type(8))) short short8v;   // 8 bf16
typedef __attribute__((ext_vector_type(4))) float f32x4;

__device__ __forceinline__ short f2bf(float f) {
    unsigned int b = __float_as_uint(f);
    b += 0x7fffu + ((b >> 16) & 1u);          // round-to-nearest-even
    return (short)(b >> 16);
}

// ---------------------------------------------------------------------------
// K1 (vnx): FUSED xpose + dihedral + node matmul + LayerNorm.
// Block = 64 threads (ONE wave), grid = 256 -> all 256 CUs busy (v2 used 64
// blocks -> 64 CUs; that was the 21 us). Node-per-lane dihedrals; per-wave
// quadratic-form LN stats (validated in R13); cooperative coalesced stores.
// Each lane also writes P[node] = (CA.xyz, mask) -- absorbs xpose_kernel.
// ---------------------------------------------------------------------------
__global__ __launch_bounds__(64) void vnx_kernel(
    const float* __restrict__ X, const float* __restrict__ mask,
    const float* __restrict__ Wn, const float* __restrict__ bn,
    const float* __restrict__ gn, const float* __restrict__ btn,
    float* __restrict__ V, float4* __restrict__ P)
{
    __shared__ float fsh[64][8];                   // 2 KB

    const int ln   = threadIdx.x;
    const int node = blockIdx.x * 64 + ln;
    const int b = node >> 11, i = node & (NL - 1);

    // ---- weights for this lane's two h-columns ----
    const int h0 = ln, h1 = ln + 64;
    float w0[6], w1[6];
    #pragma unroll
    for (int j = 0; j < 6; ++j) { w0[j] = Wn[j * NH + h0]; w1[j] = Wn[j * NH + h1]; }
    const float bb0 = bn[h0], bb1 = bn[h1];
    const float g0  = gn[h0], g1  = gn[h1];
    const float t0  = btn[h0], t1 = btn[h1];

    // ---- Phase 0: wave-reduce LN stats (35 values) ----
    float st[35];
    {
        int idx = 0;
        #pragma unroll
        for (int j = 0; j < 6; ++j)
            #pragma unroll
            for (int k = j; k < 6; ++k)
                st[idx++] = w0[j] * w0[k] + w1[j] * w1[k];     // M upper-tri
        #pragma unroll
        for (int j = 0; j < 6; ++j) st[21 + j] = w0[j] * bb0 + w1[j] * bb1; // Wb
        #pragma unroll
        for (int j = 0; j < 6; ++j) st[27 + j] = w0[j] + w1[j];             // csW
        st[33] = bb0 + bb1;
        st[34] = bb0 * bb0 + bb1 * bb1;
        #pragma unroll
        for (int q = 0; q < 35; ++q) {
            float vv = st[q];
            #pragma unroll
            for (int off = 32; off; off >>= 1) vv += __shfl_xor(vv, off);
            st[q] = vv;
        }
    }

    // ---- Phase 1: dihedral features for THIS lane's node (+ P write) ----
    const float* XB = X + (size_t)b * NL * 12;
    const int rm1 = (i >= 1) ? i - 1 : 0;
    const int rp1 = (i <= NL - 2) ? i + 1 : NL - 1;
    float p[6][3];
    {
        const int rows[6]  = { rm1, i, i, i, rp1, rp1 };
        const int atoms[6] = { 2,   0, 1, 2, 0,   1   };
        #pragma unroll
        for (int k = 0; k < 6; ++k) {
            const float* q = XB + ((size_t)rows[k] * 4 + atoms[k]) * 3;
            p[k][0] = q[0]; p[k][1] = q[1]; p[k][2] = q[2];
        }
    }
    // absorb xpose: P[node] = (CA = p[2], mask)
    P[node] = make_float4(p[2][0], p[2][1], p[2][2], mask[node]);

    float uv[5][3], nv[4][3];
    #pragma unroll
    for (int k = 0; k < 5; ++k) {
        float vx = p[k+1][0] - p[k][0];
        float vy = p[k+1][1] - p[k][1];
        float vz = p[k+1][2] - p[k][2];
        float n = sqrtf(vx*vx + vy*vy + vz*vz) + 1e-8f;
        uv[k][0] = vx / n; uv[k][1] = vy / n; uv[k][2] = vz / n;
    }
    #pragma unroll
    for (int k = 0; k < 4; ++k) {
        float cx = uv[k][1]*uv[k+1][2] - uv[k][2]*uv[k+1][1];
        float cy = uv[k][2]*uv[k+1][0] - uv[k][0]*uv[k+1][2];
        float cz = uv[k][0]*uv[k+1][1] - uv[k][1]*uv[k+1][0];
        float n = sqrtf(cx*cx + cy*cy + cz*cz) + 1e-8f;
        nv[k][0] = cx / n; nv[k][1] = cy / n; nv[k][2] = cz / n;
    }
    float f[6];
    #pragma unroll
    for (int a = 0; a < 3; ++a) {
        bool valid = (a == 0) ? (i >= 1) : (i <= NL - 2);
        float cosD = nv[a][0]*nv[a+1][0] + nv[a][1]*nv[a+1][1] + nv[a][2]*nv[a+1][2];
        cosD = fminf(fmaxf(cosD, -1.0f + 1e-7f), 1.0f - 1e-7f);
        float sg = uv[a][0]*nv[a+1][0] + uv[a][1]*nv[a+1][1] + uv[a][2]*nv[a+1][2];
        float sgn = (sg > 0.0f) ? 1.0f : ((sg < 0.0f) ? -1.0f : 0.0f);
        float an = valid ? (sgn * acosf(cosD)) : 0.0f;
        f[a]     = cosf(an);
        f[3 + a] = sinf(an);
    }

    // in-lane mean/inv via quadratic form
    float s1 = st[33];
    #pragma unroll
    for (int j = 0; j < 6; ++j) s1 = fmaf(f[j], st[27 + j], s1);
    float qd = st[34];
    #pragma unroll
    for (int j = 0; j < 6; ++j) qd = fmaf(2.0f * f[j], st[21 + j], qd);
    {
        int idx = 0;
        #pragma unroll
        for (int j = 0; j < 6; ++j)
            #pragma unroll
            for (int k = j; k < 6; ++k) {
                float coef = (j == k) ? 1.0f : 2.0f;
                qd = fmaf(coef * f[j] * f[k], st[idx], qd);
                ++idx;
            }
    }
    const float mean = s1 * (1.0f / 128.0f);
    const float var  = fmaxf(qd * (1.0f / 128.0f) - mean * mean, 0.0f);
    const float inv  = rsqrtf(var + 1e-5f);

    #pragma unroll
    for (int j = 0; j < 6; ++j) fsh[ln][j] = f[j];
    fsh[ln][6] = mean;
    fsh[ln][7] = inv;
    // single wave: write->read ordering within the wave via lgkmcnt; no barrier

    // ---- Phase 2: cooperative outputs, coalesced stores ----
    const int node_base = blockIdx.x * 64;
    for (int nn = 0; nn < 64; ++nn) {
        const float* fr = fsh[nn];
        float a0 = bb0, a1 = bb1;
        #pragma unroll
        for (int j = 0; j < 6; ++j) {
            a0 = fmaf(fr[j], w0[j], a0);
            a1 = fmaf(fr[j], w1[j], a1);
        }
        const float mn = fr[6], iv = fr[7];
        float* o = V + (size_t)(node_base + nn) * NH;
        o[h0] = (a0 - mn) * iv * g0 + t0;
        o[h1] = (a1 - mn) * iv * g1 + t1;
    }
}

// ---------------------------------------------------------------------------
// K2 (v7, identical to R13 -- 44.4 us measured): one WAVE per row,
// register-resident distances, bitonic lane-min threshold, ballot compaction,
// rank-based exact selection. key=(bits<<32)|j == lax.top_k stable order.
// ---------------------------------------------------------------------------
__global__ __launch_bounds__(256) void topk_kernel(
    const float4* __restrict__ P,
    float* __restrict__ eidx, float* __restrict__ dnb)
{
    __shared__ ull cand[4][CAND_CAP];              // 8 KB

    const int tid = threadIdx.x;
    const int wv  = tid >> 6;
    const int ln  = tid & 63;
    const int row = blockIdx.x * 4 + wv;
    const int b   = row >> 11;
    const int i   = row & (NL - 1);

    const float4* Pb = P + (size_t)b * NL;
    const float4 pi = Pb[i];
    const float xi = pi.x, yi = pi.y, zi = pi.z, mi = pi.w;

    unsigned int u[32];
    float lm0 = 0.0f, lm1 = 0.0f, lm2 = 0.0f, lm3 = 0.0f;
    #pragma unroll
    for (int t = 0; t < 32; t += 4) {
        #pragma unroll
        for (int q = 0; q < 4; ++q) {
            const float4 pj = Pb[ln + 64 * (t + q)];
            float dx = xi - pj.x;
            float dy = yi - pj.y;
            float dz = zi - pj.z;
            float s = __fadd_rn(__fmul_rn(dx, dx), __fmul_rn(dy, dy));
            s = __fadd_rn(s, __fmul_rn(dz, dz));
            s = __fadd_rn(s, 1e-6f);
            float m2 = __fmul_rn(pj.w, mi);
            float d  = __fmul_rn(m2, __fsqrt_rn(s));
            u[t + q] = __float_as_uint(d) | ((m2 == 0.0f) ? 0x80000000u : 0u);
            if      (q == 0) lm0 = fmaxf(lm0, d);
            else if (q == 1) lm1 = fmaxf(lm1, d);
            else if (q == 2) lm2 = fmaxf(lm2, d);
            else             lm3 = fmaxf(lm3, d);
        }
    }
    float lmax = fmaxf(fmaxf(lm0, lm1), fmaxf(lm2, lm3));
    #pragma unroll
    for (int off = 32; off; off >>= 1) lmax = fmaxf(lmax, __shfl_xor(lmax, off));
    const unsigned int DMB = __float_as_uint(__fadd_rn(lmax, 1.0f));

    unsigned int um0 = 0xFFFFFFFFu, um1 = 0xFFFFFFFFu,
                 um2 = 0xFFFFFFFFu, um3 = 0xFFFFFFFFu;
    #pragma unroll
    for (int t = 0; t < 32; t += 4) {
        unsigned int b0 = (u[t+0] & 0x80000000u) ? DMB : u[t+0];
        unsigned int b1 = (u[t+1] & 0x80000000u) ? DMB : u[t+1];
        unsigned int b2 = (u[t+2] & 0x80000000u) ? DMB : u[t+2];
        unsigned int b3 = (u[t+3] & 0x80000000u) ? DMB : u[t+3];
        u[t+0] = b0; u[t+1] = b1; u[t+2] = b2; u[t+3] = b3;
        um0 = min(um0, b0); um1 = min(um1, b1);
        um2 = min(um2, b2); um3 = min(um3, b3);
    }
    unsigned int umin = min(min(um0, um1), min(um2, um3));

    unsigned int v = umin;
    #pragma unroll
    for (int k = 2; k <= 64; k <<= 1) {
        #pragma unroll
        for (int j = k >> 1; j > 0; j >>= 1) {
            unsigned int o = __shfl_xor(v, j);
            bool asc   = ((ln & k) == 0);
            bool lower = ((ln & j) == 0);
            v = (lower == asc) ? min(v, o) : max(v, o);
        }
    }
    const unsigned int T = __shfl(v, TOPK - 1);

    unsigned int base = 0;
    #pragma unroll
    for (int t = 0; t < 32; ++t) {
        bool act = u[t] <= T;
        ull m = __ballot(act);
        if (act) {
            unsigned int pos = base + (unsigned)__popcll(m & ((1ull << ln) - 1ull));
            if (pos < CAND_CAP)
                cand[wv][pos] = ((ull)u[t] << 32) | (unsigned)(ln + 64 * t);
        }
        base += (unsigned)__popcll(m);
    }
    const unsigned int cnt = base;

    float* eo  = eidx + (size_t)row * TOPK;
    float* dno = dnb  + (size_t)row * TOPK;

    if (cnt <= CAND_CAP) {
        ull k0 = ((unsigned)ln        < cnt) ? cand[wv][ln]        : ~0ULL;
        ull k1 = ((unsigned)ln +  64u < cnt) ? cand[wv][ln +  64]  : ~0ULL;
        ull k2 = ((unsigned)ln + 128u < cnt) ? cand[wv][ln + 128]  : ~0ULL;
        ull k3 = ((unsigned)ln + 192u < cnt) ? cand[wv][ln + 192]  : ~0ULL;
        int r0 = 0, r1 = 0, r2 = 0, r3 = 0;
        for (unsigned int p = 0; p < cnt; p += 4) {
            ull c0 = cand[wv][p];
            ull c1 = (p + 1 < cnt) ? cand[wv][p + 1] : ~0ULL;
            ull c2 = (p + 2 < cnt) ? cand[wv][p + 2] : ~0ULL;
            ull c3 = (p + 3 < cnt) ? cand[wv][p + 3] : ~0ULL;
            r0 += (c0 < k0) + (c1 < k0) + (c2 < k0) + (c3 < k0);
            r1 += (c0 < k1) + (c1 < k1) + (c2 < k1) + (c3 < k1);
            r2 += (c0 < k2) + (c1 < k2) + (c2 < k2) + (c3 < k2);
            r3 += (c0 < k3) + (c1 < k3) + (c2 < k3) + (c3 < k3);
        }
        if (r0 < TOPK) { eo[r0] = (float)(unsigned)(k0 & 0xFFFFFFFFu); dno[r0] = __uint_as_float((unsigned)(k0 >> 32)); }
        if (r1 < TOPK) { eo[r1] = (float)(unsigned)(k1 & 0xFFFFFFFFu); dno[r1] = __uint_as_float((unsigned)(k1 >> 32)); }
        if (r2 < TOPK) { eo[r2] = (float)(unsigned)(k2 & 0xFFFFFFFFu); dno[r2] = __uint_as_float((unsigned)(k2 >> 32)); }
        if (r3 < TOPK) { eo[r3] = (float)(unsigned)(k3 & 0xFFFFFFFFu); dno[r3] = __uint_as_float((unsigned)(k3 >> 32)); }
    } else {
        ull last = 0ULL;
        for (int k = 0; k < TOPK; ++k) {
            ull best = ~0ULL;
            #pragma unroll
            for (int t = 0; t < 32; ++t) {
                ull key = ((ull)u[t] << 32) | (unsigned)(ln + 64 * t);
                if (key > last && key < best) best = key;
            }
            #pragma unroll
            for (int off = 32; off; off >>= 1) {
                ull o = __shfl_xor(best, off);
                if (o < best) best = o;
            }
            if (ln == 0) {
                eo[k]  = (float)(unsigned)(best & 0xFFFFFFFFu);
                dno[k] = __uint_as_float((unsigned)(best >> 32));
            }
            last = best;
        }
    }
}

// ---------------------------------------------------------------------------
// K3 (v2, identical to R13 -- 53.8 us measured): edge features -> MFMA
// 32x128 -> LayerNorm -> nontemporal E. Lane owns one edge; dwordx4 stores.
// ---------------------------------------------------------------------------
__global__ __launch_bounds__(256) void edge_kernel(
    const float* __restrict__ eidx, const float* __restrict__ dnb,
    const float* __restrict__ We, const float* __restrict__ be,
    const float* __restrict__ ge, const float* __restrict__ bte,
    float* __restrict__ E)
{
    const int lane = threadIdx.x & 63;
    const int c    = lane & 15;
    const int g    = lane >> 4;
    const int wid  = (int)((blockIdx.x * blockDim.x + threadIdx.x) >> 6);
    const int nw   = (int)((gridDim.x * blockDim.x) >> 6);

    short8v W[8];
    #pragma unroll
    for (int t = 0; t < 8; ++t)
        #pragma unroll
        for (int e = 0; e < 8; ++e)
            W[t][e] = f2bf(We[(g * 8 + e) * NH + t * 16 + c]);

    float fcs[8];
    #pragma unroll
    for (int e = 0; e < 8; ++e) {
        if (g < 2) fcs[e] = expf((float)(2 * e) * -0.57564627f);  // ln(1e4)/16
        else       fcs[e] = (float)((g - 2) * 8 + e) * (20.0f / 15.0f);
    }

    const int ntiles = NB * NL * TOPK / 16;
    for (int tile = wid; tile < ntiles; tile += nw) {
        const int e0   = tile * 16;
        const int edge = e0 + c;
        const float fidx = eidx[edge];
        const float Dv   = dnb[edge];
        const int   row  = edge / TOPK;
        const float d    = fidx - (float)(row & (NL - 1));

        short8v F;
        if (g == 0) {
            #pragma unroll
            for (int e = 0; e < 8; ++e) F[e] = f2bf(cosf(d * fcs[e]));
        } else if (g == 1) {
            #pragma unroll
            for (int e = 0; e < 8; ++e) F[e] = f2bf(sinf(d * fcs[e]));
        } else {
            #pragma unroll
            for (int e = 0; e < 8; ++e) {
                float tt = (Dv - fcs[e]) * 0.8f;
                F[e] = f2bf(expf(-tt * tt));
            }
        }

        f32x4 acc[8];
        const f32x4 zero = {0.0f, 0.0f, 0.0f, 0.0f};
        #pragma unroll
        for (int t = 0; t < 8; ++t)
            acc[t] = __builtin_amdgcn_mfma_f32_16x16x32_bf16(W[t], F, zero, 0, 0, 0);

        float s = 0.0f, s2 = 0.0f;
        #pragma unroll
        for (int t = 0; t < 8; ++t) {
            const f32x4 b4 = *(const f32x4*)&be[t * 16 + g * 4];
            #pragma unroll
            for (int j = 0; j < 4; ++j) {
                float vv = acc[t][j] + b4[j];
                acc[t][j] = vv;
                s  += vv;
                s2 = fmaf(vv, vv, s2);
            }
        }
        s  += __shfl_xor(s, 16);  s  += __shfl_xor(s, 32);
        s2 += __shfl_xor(s2, 16); s2 += __shfl_xor(s2, 32);
        const float mean = s * (1.0f / 128.0f);
        const float var  = fmaxf(s2 * (1.0f / 128.0f) - mean * mean, 0.0f);
        const float inv  = rsqrtf(var + 1e-5f);

        float* const Eo = E + (size_t)edge * NH;
        #pragma unroll
        for (int t = 0; t < 8; ++t) {
            const f32x4 g4  = *(const f32x4*)&ge [t * 16 + g * 4];
            const f32x4 bt4 = *(const f32x4*)&bte[t * 16 + g * 4];
            f32x4 o;
            #pragma unroll
            for (int j = 0; j < 4; ++j)
                o[j] = (acc[t][j] - mean) * inv * g4[j] + bt4[j];
            __builtin_nontemporal_store(o, (f32x4*)&Eo[t * 16 + g * 4]);
        }
    }
}

extern "C" void kernel_launch(void* const* d_in, const int* in_sizes, int n_in,
                              void* d_out, int out_size, void* d_ws, size_t ws_size,
                              hipStream_t stream)
{
    const float* X    = (const float*)d_in[0];
    const float* mask = (const float*)d_in[1];
    const float* Wn   = (const float*)d_in[2];
    const float* bn   = (const float*)d_in[3];
    const float* We   = (const float*)d_in[4];
    const float* be   = (const float*)d_in[5];
    const float* gn   = (const float*)d_in[6];
    const float* btn  = (const float*)d_in[7];
    const float* ge   = (const float*)d_in[8];
    const float* bte  = (const float*)d_in[9];

    float* out = (float*)d_out;
    float* V   = out;                                   // (8,2048,128)
    float* E   = V  + (size_t)NB * NL * NH;             // (8,2048,30,128)
    float* EI  = E  + (size_t)NB * NL * TOPK * NH;      // (8,2048,30) as float

    float4* P  = (float4*)d_ws;                         // SoA (x,y,z,m), 256 KB
    float* dnb = (float*)d_ws + 4 * (size_t)NB * NL;    // D_neighbors scratch

    hipLaunchKernelGGL(vnx_kernel,  dim3(NB * NL / 64),  dim3(64),  0, stream,
                       X, mask, Wn, bn, gn, btn, V, P);
    hipLaunchKernelGGL(topk_kernel, dim3(NB * NL / 4),   dim3(256), 0, stream,
                       P, EI, dnb);
    hipLaunchKernelGGL(edge_kernel, dim3(1920),          dim3(256), 0, stream,
                       EI, dnb, We, be, ge, bte, E);
}

// Round 15
// 129.794 us; speedup vs baseline: 2.4413x; 1.0788x over previous
//
#include <hip/hip_runtime.h>
#include <cstdint>
#include <cstddef>

#define NB 8
#define NL 2048
#define TOPK 30
#define NH 128
#define CAND_CAP 256

typedef unsigned long long ull;
typedef __attribute__((ext_vector_type(8))) short short8v;   // 8 bf16
typedef __attribute__((ext_vector_type(4))) float f32x4;

__device__ __forceinline__ short f2bf(float f) {
    unsigned int b = __float_as_uint(f);
    b += 0x7fffu + ((b >> 16) & 1u);          // round-to-nearest-even
    return (short)(b >> 16);
}

// ---------------------------------------------------------------------------
// K1 (vnx v4): FUSED xpose + dihedral + node matmul + LayerNorm.
// 256-thread blocks (4 waves/CU), grid 256 -> all CUs AND intra-CU TLP.
// Wave 0: LN stats (quadratic form, validated R13) + node-per-lane dihedrals
// for the block's 64 nodes + P[node] write. Barrier. Phase 2: all 4 waves,
// 8 passes, 32-thread group per node, 4 h-cols per thread, f32x4 stores
// (1 KB contiguous per wave instruction).
// ---------------------------------------------------------------------------
__global__ __launch_bounds__(256) void vnx_kernel(
    const float* __restrict__ X, const float* __restrict__ mask,
    const float* __restrict__ Wn, const float* __restrict__ bn,
    const float* __restrict__ gn, const float* __restrict__ btn,
    float* __restrict__ V, float4* __restrict__ P)
{
    __shared__ float fsh[64][8];                   // 2 KB

    const int tid = threadIdx.x;
    const int node_base = blockIdx.x * 64;

    if (tid < 64) {
        const int ln   = tid;
        const int node = node_base + ln;
        const int b = node >> 11, i = node & (NL - 1);

        // weights for this lane's two h-columns (stats only)
        const int h0 = ln, h1 = ln + 64;
        float w0[6], w1[6];
        #pragma unroll
        for (int j = 0; j < 6; ++j) { w0[j] = Wn[j * NH + h0]; w1[j] = Wn[j * NH + h1]; }
        const float bb0 = bn[h0], bb1 = bn[h1];

        // ---- Phase 0: wave-reduce LN stats (35 values) ----
        float st[35];
        {
            int idx = 0;
            #pragma unroll
            for (int j = 0; j < 6; ++j)
                #pragma unroll
                for (int k = j; k < 6; ++k)
                    st[idx++] = w0[j] * w0[k] + w1[j] * w1[k];     // M upper-tri
            #pragma unroll
            for (int j = 0; j < 6; ++j) st[21 + j] = w0[j] * bb0 + w1[j] * bb1; // Wb
            #pragma unroll
            for (int j = 0; j < 6; ++j) st[27 + j] = w0[j] + w1[j];             // csW
            st[33] = bb0 + bb1;
            st[34] = bb0 * bb0 + bb1 * bb1;
            #pragma unroll
            for (int q = 0; q < 35; ++q) {
                float vv = st[q];
                #pragma unroll
                for (int off = 32; off; off >>= 1) vv += __shfl_xor(vv, off);
                st[q] = vv;
            }
        }

        // ---- Phase 1: dihedrals for THIS lane's node (+ P write) ----
        const float* XB = X + (size_t)b * NL * 12;
        const int rm1 = (i >= 1) ? i - 1 : 0;
        const int rp1 = (i <= NL - 2) ? i + 1 : NL - 1;
        float p[6][3];
        {
            const int rows[6]  = { rm1, i, i, i, rp1, rp1 };
            const int atoms[6] = { 2,   0, 1, 2, 0,   1   };
            #pragma unroll
            for (int k = 0; k < 6; ++k) {
                const float* q = XB + ((size_t)rows[k] * 4 + atoms[k]) * 3;
                p[k][0] = q[0]; p[k][1] = q[1]; p[k][2] = q[2];
            }
        }
        P[node] = make_float4(p[2][0], p[2][1], p[2][2], mask[node]);

        float uv[5][3], nv[4][3];
        #pragma unroll
        for (int k = 0; k < 5; ++k) {
            float vx = p[k+1][0] - p[k][0];
            float vy = p[k+1][1] - p[k][1];
            float vz = p[k+1][2] - p[k][2];
            float n = sqrtf(vx*vx + vy*vy + vz*vz) + 1e-8f;
            uv[k][0] = vx / n; uv[k][1] = vy / n; uv[k][2] = vz / n;
        }
        #pragma unroll
        for (int k = 0; k < 4; ++k) {
            float cx = uv[k][1]*uv[k+1][2] - uv[k][2]*uv[k+1][1];
            float cy = uv[k][2]*uv[k+1][0] - uv[k][0]*uv[k+1][2];
            float cz = uv[k][0]*uv[k+1][1] - uv[k][1]*uv[k+1][0];
            float n = sqrtf(cx*cx + cy*cy + cz*cz) + 1e-8f;
            nv[k][0] = cx / n; nv[k][1] = cy / n; nv[k][2] = cz / n;
        }
        float f[6];
        #pragma unroll
        for (int a = 0; a < 3; ++a) {
            bool valid = (a == 0) ? (i >= 1) : (i <= NL - 2);
            float cosD = nv[a][0]*nv[a+1][0] + nv[a][1]*nv[a+1][1] + nv[a][2]*nv[a+1][2];
            cosD = fminf(fmaxf(cosD, -1.0f + 1e-7f), 1.0f - 1e-7f);
            float sg = uv[a][0]*nv[a+1][0] + uv[a][1]*nv[a+1][1] + uv[a][2]*nv[a+1][2];
            float sgn = (sg > 0.0f) ? 1.0f : ((sg < 0.0f) ? -1.0f : 0.0f);
            float an = valid ? (sgn * acosf(cosD)) : 0.0f;
            f[a]     = cosf(an);
            f[3 + a] = sinf(an);
        }

        // in-lane mean/inv via quadratic form
        float s1 = st[33];
        #pragma unroll
        for (int j = 0; j < 6; ++j) s1 = fmaf(f[j], st[27 + j], s1);
        float qd = st[34];
        #pragma unroll
        for (int j = 0; j < 6; ++j) qd = fmaf(2.0f * f[j], st[21 + j], qd);
        {
            int idx = 0;
            #pragma unroll
            for (int j = 0; j < 6; ++j)
                #pragma unroll
                for (int k = j; k < 6; ++k) {
                    float coef = (j == k) ? 1.0f : 2.0f;
                    qd = fmaf(coef * f[j] * f[k], st[idx], qd);
                    ++idx;
                }
        }
        const float mean = s1 * (1.0f / 128.0f);
        const float var  = fmaxf(qd * (1.0f / 128.0f) - mean * mean, 0.0f);
        const float inv  = rsqrtf(var + 1e-5f);

        #pragma unroll
        for (int j = 0; j < 6; ++j) fsh[ln][j] = f[j];
        fsh[ln][6] = mean;
        fsh[ln][7] = inv;
    }
    __syncthreads();

    // ---- Phase 2: all 256 threads; 4 h-cols each; 1 KB/wave-instr stores ----
    const int m  = tid & 31;            // col group within node
    const int ng = tid >> 5;            // node sub-index (0..7)
    const int h4 = m * 4;
    f32x4 w4[6];
    #pragma unroll
    for (int j = 0; j < 6; ++j) w4[j] = *(const f32x4*)&Wn[j * NH + h4];
    const f32x4 b4  = *(const f32x4*)&bn [h4];
    const f32x4 g4  = *(const f32x4*)&gn [h4];
    const f32x4 bt4 = *(const f32x4*)&btn[h4];

    #pragma unroll
    for (int it = 0; it < 8; ++it) {
        const int nn = it * 8 + ng;
        const float* fr = fsh[nn];
        f32x4 a = b4;
        #pragma unroll
        for (int j = 0; j < 6; ++j) {
            const float fj = fr[j];
            #pragma unroll
            for (int x = 0; x < 4; ++x) a[x] = fmaf(fj, w4[j][x], a[x]);
        }
        const float mn = fr[6], iv = fr[7];
        f32x4 o;
        #pragma unroll
        for (int x = 0; x < 4; ++x) o[x] = (a[x] - mn) * iv * g4[x] + bt4[x];
        *(f32x4*)&V[(size_t)(node_base + nn) * NH + h4] = o;
    }
}

// ---------------------------------------------------------------------------
// K2 (v7, byte-identical to R13/R14 -- 44.4 us measured): one WAVE per row.
// ---------------------------------------------------------------------------
__global__ __launch_bounds__(256) void topk_kernel(
    const float4* __restrict__ P,
    float* __restrict__ eidx, float* __restrict__ dnb)
{
    __shared__ ull cand[4][CAND_CAP];              // 8 KB

    const int tid = threadIdx.x;
    const int wv  = tid >> 6;
    const int ln  = tid & 63;
    const int row = blockIdx.x * 4 + wv;
    const int b   = row >> 11;
    const int i   = row & (NL - 1);

    const float4* Pb = P + (size_t)b * NL;
    const float4 pi = Pb[i];
    const float xi = pi.x, yi = pi.y, zi = pi.z, mi = pi.w;

    unsigned int u[32];
    float lm0 = 0.0f, lm1 = 0.0f, lm2 = 0.0f, lm3 = 0.0f;
    #pragma unroll
    for (int t = 0; t < 32; t += 4) {
        #pragma unroll
        for (int q = 0; q < 4; ++q) {
            const float4 pj = Pb[ln + 64 * (t + q)];
            float dx = xi - pj.x;
            float dy = yi - pj.y;
            float dz = zi - pj.z;
            float s = __fadd_rn(__fmul_rn(dx, dx), __fmul_rn(dy, dy));
            s = __fadd_rn(s, __fmul_rn(dz, dz));
            s = __fadd_rn(s, 1e-6f);
            float m2 = __fmul_rn(pj.w, mi);
            float d  = __fmul_rn(m2, __fsqrt_rn(s));
            u[t + q] = __float_as_uint(d) | ((m2 == 0.0f) ? 0x80000000u : 0u);
            if      (q == 0) lm0 = fmaxf(lm0, d);
            else if (q == 1) lm1 = fmaxf(lm1, d);
            else if (q == 2) lm2 = fmaxf(lm2, d);
            else             lm3 = fmaxf(lm3, d);
        }
    }
    float lmax = fmaxf(fmaxf(lm0, lm1), fmaxf(lm2, lm3));
    #pragma unroll
    for (int off = 32; off; off >>= 1) lmax = fmaxf(lmax, __shfl_xor(lmax, off));
    const unsigned int DMB = __float_as_uint(__fadd_rn(lmax, 1.0f));

    unsigned int um0 = 0xFFFFFFFFu, um1 = 0xFFFFFFFFu,
                 um2 = 0xFFFFFFFFu, um3 = 0xFFFFFFFFu;
    #pragma unroll
    for (int t = 0; t < 32; t += 4) {
        unsigned int b0 = (u[t+0] & 0x80000000u) ? DMB : u[t+0];
        unsigned int b1 = (u[t+1] & 0x80000000u) ? DMB : u[t+1];
        unsigned int b2 = (u[t+2] & 0x80000000u) ? DMB : u[t+2];
        unsigned int b3 = (u[t+3] & 0x80000000u) ? DMB : u[t+3];
        u[t+0] = b0; u[t+1] = b1; u[t+2] = b2; u[t+3] = b3;
        um0 = min(um0, b0); um1 = min(um1, b1);
        um2 = min(um2, b2); um3 = min(um3, b3);
    }
    unsigned int umin = min(min(um0, um1), min(um2, um3));

    unsigned int v = umin;
    #pragma unroll
    for (int k = 2; k <= 64; k <<= 1) {
        #pragma unroll
        for (int j = k >> 1; j > 0; j >>= 1) {
            unsigned int o = __shfl_xor(v, j);
            bool asc   = ((ln & k) == 0);
            bool lower = ((ln & j) == 0);
            v = (lower == asc) ? min(v, o) : max(v, o);
        }
    }
    const unsigned int T = __shfl(v, TOPK - 1);

    unsigned int base = 0;
    #pragma unroll
    for (int t = 0; t < 32; ++t) {
        bool act = u[t] <= T;
        ull m = __ballot(act);
        if (act) {
            unsigned int pos = base + (unsigned)__popcll(m & ((1ull << ln) - 1ull));
            if (pos < CAND_CAP)
                cand[wv][pos] = ((ull)u[t] << 32) | (unsigned)(ln + 64 * t);
        }
        base += (unsigned)__popcll(m);
    }
    const unsigned int cnt = base;

    float* eo  = eidx + (size_t)row * TOPK;
    float* dno = dnb  + (size_t)row * TOPK;

    if (cnt <= CAND_CAP) {
        ull k0 = ((unsigned)ln        < cnt) ? cand[wv][ln]        : ~0ULL;
        ull k1 = ((unsigned)ln +  64u < cnt) ? cand[wv][ln +  64]  : ~0ULL;
        ull k2 = ((unsigned)ln + 128u < cnt) ? cand[wv][ln + 128]  : ~0ULL;
        ull k3 = ((unsigned)ln + 192u < cnt) ? cand[wv][ln + 192]  : ~0ULL;
        int r0 = 0, r1 = 0, r2 = 0, r3 = 0;
        for (unsigned int p = 0; p < cnt; p += 4) {
            ull c0 = cand[wv][p];
            ull c1 = (p + 1 < cnt) ? cand[wv][p + 1] : ~0ULL;
            ull c2 = (p + 2 < cnt) ? cand[wv][p + 2] : ~0ULL;
            ull c3 = (p + 3 < cnt) ? cand[wv][p + 3] : ~0ULL;
            r0 += (c0 < k0) + (c1 < k0) + (c2 < k0) + (c3 < k0);
            r1 += (c0 < k1) + (c1 < k1) + (c2 < k1) + (c3 < k1);
            r2 += (c0 < k2) + (c1 < k2) + (c2 < k2) + (c3 < k2);
            r3 += (c0 < k3) + (c1 < k3) + (c2 < k3) + (c3 < k3);
        }
        if (r0 < TOPK) { eo[r0] = (float)(unsigned)(k0 & 0xFFFFFFFFu); dno[r0] = __uint_as_float((unsigned)(k0 >> 32)); }
        if (r1 < TOPK) { eo[r1] = (float)(unsigned)(k1 & 0xFFFFFFFFu); dno[r1] = __uint_as_float((unsigned)(k1 >> 32)); }
        if (r2 < TOPK) { eo[r2] = (float)(unsigned)(k2 & 0xFFFFFFFFu); dno[r2] = __uint_as_float((unsigned)(k2 >> 32)); }
        if (r3 < TOPK) { eo[r3] = (float)(unsigned)(k3 & 0xFFFFFFFFu); dno[r3] = __uint_as_float((unsigned)(k3 >> 32)); }
    } else {
        ull last = 0ULL;
        for (int k = 0; k < TOPK; ++k) {
            ull best = ~0ULL;
            #pragma unroll
            for (int t = 0; t < 32; ++t) {
                ull key = ((ull)u[t] << 32) | (unsigned)(ln + 64 * t);
                if (key > last && key < best) best = key;
            }
            #pragma unroll
            for (int off = 32; off; off >>= 1) {
                ull o = __shfl_xor(best, off);
                if (o < best) best = o;
            }
            if (ln == 0) {
                eo[k]  = (float)(unsigned)(best & 0xFFFFFFFFu);
                dno[k] = __uint_as_float((unsigned)(best >> 32));
            }
            last = best;
        }
    }
}

// ---------------------------------------------------------------------------
// K3 (v4): edge features -> MFMA 32x128 -> LayerNorm -> LDS transpose ->
// 1KB-contiguous nontemporal stores. Wave-local LDS tile [16][132] (pad 132
// keeps 16B alignment for b128 ops, decollides banks). No barrier needed
// (same-wave write->read, lgkmcnt ordering).
// ---------------------------------------------------------------------------
__global__ __launch_bounds__(256) void edge_kernel(
    const float* __restrict__ eidx, const float* __restrict__ dnb,
    const float* __restrict__ We, const float* __restrict__ be,
    const float* __restrict__ ge, const float* __restrict__ bte,
    float* __restrict__ E)
{
    __shared__ float ebuf[4][16][132];             // 33 KB
    const int lane = threadIdx.x & 63;
    const int wv   = threadIdx.x >> 6;
    const int c    = lane & 15;
    const int g    = lane >> 4;
    const int wid  = (int)((blockIdx.x * blockDim.x + threadIdx.x) >> 6);
    const int nw   = (int)((gridDim.x * blockDim.x) >> 6);

    short8v W[8];
    #pragma unroll
    for (int t = 0; t < 8; ++t)
        #pragma unroll
        for (int e = 0; e < 8; ++e)
            W[t][e] = f2bf(We[(g * 8 + e) * NH + t * 16 + c]);

    float fcs[8];
    #pragma unroll
    for (int e = 0; e < 8; ++e) {
        if (g < 2) fcs[e] = expf((float)(2 * e) * -0.57564627f);  // ln(1e4)/16
        else       fcs[e] = (float)((g - 2) * 8 + e) * (20.0f / 15.0f);
    }

    const int ntiles = NB * NL * TOPK / 16;
    for (int tile = wid; tile < ntiles; tile += nw) {
        const int e0   = tile * 16;
        const int edge = e0 + c;
        const float fidx = eidx[edge];
        const float Dv   = dnb[edge];
        const int   row  = edge / TOPK;
        const float d    = fidx - (float)(row & (NL - 1));

        short8v F;
        if (g == 0) {
            #pragma unroll
            for (int e = 0; e < 8; ++e) F[e] = f2bf(cosf(d * fcs[e]));
        } else if (g == 1) {
            #pragma unroll
            for (int e = 0; e < 8; ++e) F[e] = f2bf(sinf(d * fcs[e]));
        } else {
            #pragma unroll
            for (int e = 0; e < 8; ++e) {
                float tt = (Dv - fcs[e]) * 0.8f;
                F[e] = f2bf(expf(-tt * tt));
            }
        }

        f32x4 acc[8];
        const f32x4 zero = {0.0f, 0.0f, 0.0f, 0.0f};
        #pragma unroll
        for (int t = 0; t < 8; ++t)
            acc[t] = __builtin_amdgcn_mfma_f32_16x16x32_bf16(W[t], F, zero, 0, 0, 0);

        float s = 0.0f, s2 = 0.0f;
        #pragma unroll
        for (int t = 0; t < 8; ++t) {
            const f32x4 b4 = *(const f32x4*)&be[t * 16 + g * 4];
            #pragma unroll
            for (int j = 0; j < 4; ++j) {
                float vv = acc[t][j] + b4[j];
                acc[t][j] = vv;
                s  += vv;
                s2 = fmaf(vv, vv, s2);
            }
        }
        s  += __shfl_xor(s, 16);  s  += __shfl_xor(s, 32);
        s2 += __shfl_xor(s2, 16); s2 += __shfl_xor(s2, 32);
        const float mean = s * (1.0f / 128.0f);
        const float var  = fmaxf(s2 * (1.0f / 128.0f) - mean * mean, 0.0f);
        const float inv  = rsqrtf(var + 1e-5f);

        // LN-applied values -> wave-local LDS (transposed layout source)
        #pragma unroll
        for (int t = 0; t < 8; ++t) {
            const f32x4 g4  = *(const f32x4*)&ge [t * 16 + g * 4];
            const f32x4 bt4 = *(const f32x4*)&bte[t * 16 + g * 4];
            f32x4 o;
            #pragma unroll
            for (int j = 0; j < 4; ++j)
                o[j] = (acc[t][j] - mean) * inv * g4[j] + bt4[j];
            *(f32x4*)&ebuf[wv][c][t * 16 + g * 4] = o;
        }

        // transpose read + contiguous 1KB-per-instruction stores
        float* const Ebase = E + (size_t)e0 * NH;
        #pragma unroll
        for (int q = 0; q < 8; ++q) {
            const int fi = q * 256 + lane * 4;     // float index within 16x128 tile
            const int ce = fi >> 7;
            const int id = fi & 127;
            const f32x4 o = *(const f32x4*)&ebuf[wv][ce][id];
            __builtin_nontemporal_store(o, (f32x4*)&Ebase[(size_t)ce * NH + id]);
        }
    }
}

extern "C" void kernel_launch(void* const* d_in, const int* in_sizes, int n_in,
                              void* d_out, int out_size, void* d_ws, size_t ws_size,
                              hipStream_t stream)
{
    const float* X    = (const float*)d_in[0];
    const float* mask = (const float*)d_in[1];
    const float* Wn   = (const float*)d_in[2];
    const float* bn   = (const float*)d_in[3];
    const float* We   = (const float*)d_in[4];
    const float* be   = (const float*)d_in[5];
    const float* gn   = (const float*)d_in[6];
    const float* btn  = (const float*)d_in[7];
    const float* ge   = (const float*)d_in[8];
    const float* bte  = (const float*)d_in[9];

    float* out = (float*)d_out;
    float* V   = out;                                   // (8,2048,128)
    float* E   = V  + (size_t)NB * NL * NH;             // (8,2048,30,128)
    float* EI  = E  + (size_t)NB * NL * TOPK * NH;      // (8,2048,30) as float

    float4* P  = (float4*)d_ws;                         // SoA (x,y,z,m), 256 KB
    float* dnb = (float*)d_ws + 4 * (size_t)NB * NL;    // D_neighbors scratch

    hipLaunchKernelGGL(vnx_kernel,  dim3(NB * NL / 64),  dim3(256), 0, stream,
                       X, mask, Wn, bn, gn, btn, V, P);
    hipLaunchKernelGGL(topk_kernel, dim3(NB * NL / 4),   dim3(256), 0, stream,
                       P, EI, dnb);
    hipLaunchKernelGGL(edge_kernel, dim3(1920),          dim3(256), 0, stream,
                       EI, dnb, We, be, ge, bte, E);
}

// Round 16
// 120.435 us; speedup vs baseline: 2.6310x; 1.0777x over previous
//
#include <hip/hip_runtime.h>
#include <cstdint>
#include <cstddef>

#define NB 8
#define NL 2048
#define TOPK 30
#define NH 128
#define CAND_CAP 256

typedef unsigned long long ull;
typedef __attribute__((ext_vector_type(8))) short short8v;   // 8 bf16
typedef __attribute__((ext_vector_type(4))) float f32x4;

__device__ __forceinline__ short f2bf(float f) {
    unsigned int b = __float_as_uint(f);
    b += 0x7fffu + ((b >> 16) & 1u);          // round-to-nearest-even
    return (short)(b >> 16);
}

// ---------------------------------------------------------------------------
// K1 (vnx v4, identical to R15 -- ~7 us): FUSED xpose + dihedral + node
// matmul + LayerNorm. 256-thread blocks; wave-0 dihedrals node-per-lane +
// quadratic-form LN stats; barrier; all 4 waves do coalesced f32x4 V stores.
// ---------------------------------------------------------------------------
__global__ __launch_bounds__(256) void vnx_kernel(
    const float* __restrict__ X, const float* __restrict__ mask,
    const float* __restrict__ Wn, const float* __restrict__ bn,
    const float* __restrict__ gn, const float* __restrict__ btn,
    float* __restrict__ V, float4* __restrict__ P)
{
    __shared__ float fsh[64][8];                   // 2 KB

    const int tid = threadIdx.x;
    const int node_base = blockIdx.x * 64;

    if (tid < 64) {
        const int ln   = tid;
        const int node = node_base + ln;
        const int b = node >> 11, i = node & (NL - 1);

        const int h0 = ln, h1 = ln + 64;
        float w0[6], w1[6];
        #pragma unroll
        for (int j = 0; j < 6; ++j) { w0[j] = Wn[j * NH + h0]; w1[j] = Wn[j * NH + h1]; }
        const float bb0 = bn[h0], bb1 = bn[h1];

        // ---- Phase 0: wave-reduce LN stats (35 values) ----
        float st[35];
        {
            int idx = 0;
            #pragma unroll
            for (int j = 0; j < 6; ++j)
                #pragma unroll
                for (int k = j; k < 6; ++k)
                    st[idx++] = w0[j] * w0[k] + w1[j] * w1[k];     // M upper-tri
            #pragma unroll
            for (int j = 0; j < 6; ++j) st[21 + j] = w0[j] * bb0 + w1[j] * bb1; // Wb
            #pragma unroll
            for (int j = 0; j < 6; ++j) st[27 + j] = w0[j] + w1[j];             // csW
            st[33] = bb0 + bb1;
            st[34] = bb0 * bb0 + bb1 * bb1;
            #pragma unroll
            for (int q = 0; q < 35; ++q) {
                float vv = st[q];
                #pragma unroll
                for (int off = 32; off; off >>= 1) vv += __shfl_xor(vv, off);
                st[q] = vv;
            }
        }

        // ---- Phase 1: dihedrals for THIS lane's node (+ P write) ----
        const float* XB = X + (size_t)b * NL * 12;
        const int rm1 = (i >= 1) ? i - 1 : 0;
        const int rp1 = (i <= NL - 2) ? i + 1 : NL - 1;
        float p[6][3];
        {
            const int rows[6]  = { rm1, i, i, i, rp1, rp1 };
            const int atoms[6] = { 2,   0, 1, 2, 0,   1   };
            #pragma unroll
            for (int k = 0; k < 6; ++k) {
                const float* q = XB + ((size_t)rows[k] * 4 + atoms[k]) * 3;
                p[k][0] = q[0]; p[k][1] = q[1]; p[k][2] = q[2];
            }
        }
        P[node] = make_float4(p[2][0], p[2][1], p[2][2], mask[node]);

        float uv[5][3], nv[4][3];
        #pragma unroll
        for (int k = 0; k < 5; ++k) {
            float vx = p[k+1][0] - p[k][0];
            float vy = p[k+1][1] - p[k][1];
            float vz = p[k+1][2] - p[k][2];
            float n = sqrtf(vx*vx + vy*vy + vz*vz) + 1e-8f;
            uv[k][0] = vx / n; uv[k][1] = vy / n; uv[k][2] = vz / n;
        }
        #pragma unroll
        for (int k = 0; k < 4; ++k) {
            float cx = uv[k][1]*uv[k+1][2] - uv[k][2]*uv[k+1][1];
            float cy = uv[k][2]*uv[k+1][0] - uv[k][0]*uv[k+1][2];
            float cz = uv[k][0]*uv[k+1][1] - uv[k][1]*uv[k+1][0];
            float n = sqrtf(cx*cx + cy*cy + cz*cz) + 1e-8f;
            nv[k][0] = cx / n; nv[k][1] = cy / n; nv[k][2] = cz / n;
        }
        float f[6];
        #pragma unroll
        for (int a = 0; a < 3; ++a) {
            bool valid = (a == 0) ? (i >= 1) : (i <= NL - 2);
            float cosD = nv[a][0]*nv[a+1][0] + nv[a][1]*nv[a+1][1] + nv[a][2]*nv[a+1][2];
            cosD = fminf(fmaxf(cosD, -1.0f + 1e-7f), 1.0f - 1e-7f);
            float sg = uv[a][0]*nv[a+1][0] + uv[a][1]*nv[a+1][1] + uv[a][2]*nv[a+1][2];
            float sgn = (sg > 0.0f) ? 1.0f : ((sg < 0.0f) ? -1.0f : 0.0f);
            float an = valid ? (sgn * acosf(cosD)) : 0.0f;
            f[a]     = cosf(an);
            f[3 + a] = sinf(an);
        }

        float s1 = st[33];
        #pragma unroll
        for (int j = 0; j < 6; ++j) s1 = fmaf(f[j], st[27 + j], s1);
        float qd = st[34];
        #pragma unroll
        for (int j = 0; j < 6; ++j) qd = fmaf(2.0f * f[j], st[21 + j], qd);
        {
            int idx = 0;
            #pragma unroll
            for (int j = 0; j < 6; ++j)
                #pragma unroll
                for (int k = j; k < 6; ++k) {
                    float coef = (j == k) ? 1.0f : 2.0f;
                    qd = fmaf(coef * f[j] * f[k], st[idx], qd);
                    ++idx;
                }
        }
        const float mean = s1 * (1.0f / 128.0f);
        const float var  = fmaxf(qd * (1.0f / 128.0f) - mean * mean, 0.0f);
        const float inv  = rsqrtf(var + 1e-5f);

        #pragma unroll
        for (int j = 0; j < 6; ++j) fsh[ln][j] = f[j];
        fsh[ln][6] = mean;
        fsh[ln][7] = inv;
    }
    __syncthreads();

    // ---- Phase 2: all 256 threads; 4 h-cols each; 1 KB/wave-instr stores ----
    const int m  = tid & 31;
    const int ng = tid >> 5;
    const int h4 = m * 4;
    f32x4 w4[6];
    #pragma unroll
    for (int j = 0; j < 6; ++j) w4[j] = *(const f32x4*)&Wn[j * NH + h4];
    const f32x4 b4  = *(const f32x4*)&bn [h4];
    const f32x4 g4  = *(const f32x4*)&gn [h4];
    const f32x4 bt4 = *(const f32x4*)&btn[h4];

    #pragma unroll
    for (int it = 0; it < 8; ++it) {
        const int nn = it * 8 + ng;
        const float* fr = fsh[nn];
        f32x4 a = b4;
        #pragma unroll
        for (int j = 0; j < 6; ++j) {
            const float fj = fr[j];
            #pragma unroll
            for (int x = 0; x < 4; ++x) a[x] = fmaf(fj, w4[j][x], a[x]);
        }
        const float mn = fr[6], iv = fr[7];
        f32x4 o;
        #pragma unroll
        for (int x = 0; x < 4; ++x) o[x] = (a[x] - mn) * iv * g4[x] + bt4[x];
        *(f32x4*)&V[(size_t)(node_base + nn) * NH + h4] = o;
    }
}

// ---------------------------------------------------------------------------
// K2 (v8): topk with COOPERATIVE LDS STAGING. The block's 4 rows share one
// batch: stage Ps[2048] (32 KB) once (256-thread coalesced dwordx4), one
// barrier, then P1 reads LDS (ds_read_b128) instead of 4x redundant L2
// streams. Selection logic (P2-P5) byte-identical to v7: bitonic lane-min
// threshold, ballot compaction, rank-based exact selection;
// key=(bits<<32)|j == lax.top_k stable order; exact fallback on overflow.
// ---------------------------------------------------------------------------
__global__ __launch_bounds__(256) void topk_kernel(
    const float4* __restrict__ P,
    float* __restrict__ eidx, float* __restrict__ dnb)
{
    __shared__ float4 Ps[NL];                      // 32 KB
    __shared__ ull cand[4][CAND_CAP];              // 8 KB

    const int tid = threadIdx.x;
    const int wv  = tid >> 6;
    const int ln  = tid & 63;
    const int row = blockIdx.x * 4 + wv;
    const int b   = row >> 11;
    const int i   = row & (NL - 1);

    // ---- stage the batch's packed points (the block's only barrier) ----
    const float4* Pb = P + (size_t)b * NL;
    #pragma unroll
    for (int q = 0; q < 8; ++q) Ps[tid + 256 * q] = Pb[tid + 256 * q];
    __syncthreads();

    const float4 pi = Ps[i];
    const float xi = pi.x, yi = pi.y, zi = pi.z, mi = pi.w;

    // ---- P1: distances once from LDS; mask flag in sign bit; 4-way chains --
    unsigned int u[32];
    float lm0 = 0.0f, lm1 = 0.0f, lm2 = 0.0f, lm3 = 0.0f;
    #pragma unroll
    for (int t = 0; t < 32; t += 4) {
        #pragma unroll
        for (int q = 0; q < 4; ++q) {
            const float4 pj = Ps[ln + 64 * (t + q)];
            float dx = xi - pj.x;
            float dy = yi - pj.y;
            float dz = zi - pj.z;
            float s = __fadd_rn(__fmul_rn(dx, dx), __fmul_rn(dy, dy));
            s = __fadd_rn(s, __fmul_rn(dz, dz));
            s = __fadd_rn(s, 1e-6f);
            float m2 = __fmul_rn(pj.w, mi);
            float d  = __fmul_rn(m2, __fsqrt_rn(s));
            u[t + q] = __float_as_uint(d) | ((m2 == 0.0f) ? 0x80000000u : 0u);
            if      (q == 0) lm0 = fmaxf(lm0, d);
            else if (q == 1) lm1 = fmaxf(lm1, d);
            else if (q == 2) lm2 = fmaxf(lm2, d);
            else             lm3 = fmaxf(lm3, d);
        }
    }
    float lmax = fmaxf(fmaxf(lm0, lm1), fmaxf(lm2, lm3));
    #pragma unroll
    for (int off = 32; off; off >>= 1) lmax = fmaxf(lmax, __shfl_xor(lmax, off));
    const unsigned int DMB = __float_as_uint(__fadd_rn(lmax, 1.0f));

    // ---- P2: adjusted bits via select + per-lane min (4-way chains) ----
    unsigned int um0 = 0xFFFFFFFFu, um1 = 0xFFFFFFFFu,
                 um2 = 0xFFFFFFFFu, um3 = 0xFFFFFFFFu;
    #pragma unroll
    for (int t = 0; t < 32; t += 4) {
        unsigned int b0 = (u[t+0] & 0x80000000u) ? DMB : u[t+0];
        unsigned int b1 = (u[t+1] & 0x80000000u) ? DMB : u[t+1];
        unsigned int b2 = (u[t+2] & 0x80000000u) ? DMB : u[t+2];
        unsigned int b3 = (u[t+3] & 0x80000000u) ? DMB : u[t+3];
        u[t+0] = b0; u[t+1] = b1; u[t+2] = b2; u[t+3] = b3;
        um0 = min(um0, b0); um1 = min(um1, b1);
        um2 = min(um2, b2); um3 = min(um3, b3);
    }
    unsigned int umin = min(min(um0, um1), min(um2, um3));

    // ---- P3: bitonic sort of 64 lane-minima -> threshold T at rank 29 ----
    unsigned int v = umin;
    #pragma unroll
    for (int k = 2; k <= 64; k <<= 1) {
        #pragma unroll
        for (int j = k >> 1; j > 0; j >>= 1) {
            unsigned int o = __shfl_xor(v, j);
            bool asc   = ((ln & k) == 0);
            bool lower = ((ln & j) == 0);
            v = (lower == asc) ? min(v, o) : max(v, o);
        }
    }
    const unsigned int T = __shfl(v, TOPK - 1);

    // ---- P4: ordered ballot compaction ----
    unsigned int base = 0;
    #pragma unroll
    for (int t = 0; t < 32; ++t) {
        bool act = u[t] <= T;
        ull m = __ballot(act);
        if (act) {
            unsigned int pos = base + (unsigned)__popcll(m & ((1ull << ln) - 1ull));
            if (pos < CAND_CAP)
                cand[wv][pos] = ((ull)u[t] << 32) | (unsigned)(ln + 64 * t);
        }
        base += (unsigned)__popcll(m);
    }
    const unsigned int cnt = base;

    float* eo  = eidx + (size_t)row * TOPK;
    float* dno = dnb  + (size_t)row * TOPK;

    if (cnt <= CAND_CAP) {
        // ---- P5: rank-based exact selection, unrolled x4 ----
        ull k0 = ((unsigned)ln        < cnt) ? cand[wv][ln]        : ~0ULL;
        ull k1 = ((unsigned)ln +  64u < cnt) ? cand[wv][ln +  64]  : ~0ULL;
        ull k2 = ((unsigned)ln + 128u < cnt) ? cand[wv][ln + 128]  : ~0ULL;
        ull k3 = ((unsigned)ln + 192u < cnt) ? cand[wv][ln + 192]  : ~0ULL;
        int r0 = 0, r1 = 0, r2 = 0, r3 = 0;
        for (unsigned int p = 0; p < cnt; p += 4) {
            ull c0 = cand[wv][p];
            ull c1 = (p + 1 < cnt) ? cand[wv][p + 1] : ~0ULL;
            ull c2 = (p + 2 < cnt) ? cand[wv][p + 2] : ~0ULL;
            ull c3 = (p + 3 < cnt) ? cand[wv][p + 3] : ~0ULL;
            r0 += (c0 < k0) + (c1 < k0) + (c2 < k0) + (c3 < k0);
            r1 += (c0 < k1) + (c1 < k1) + (c2 < k1) + (c3 < k1);
            r2 += (c0 < k2) + (c1 < k2) + (c2 < k2) + (c3 < k2);
            r3 += (c0 < k3) + (c1 < k3) + (c2 < k3) + (c3 < k3);
        }
        if (r0 < TOPK) { eo[r0] = (float)(unsigned)(k0 & 0xFFFFFFFFu); dno[r0] = __uint_as_float((unsigned)(k0 >> 32)); }
        if (r1 < TOPK) { eo[r1] = (float)(unsigned)(k1 & 0xFFFFFFFFu); dno[r1] = __uint_as_float((unsigned)(k1 >> 32)); }
        if (r2 < TOPK) { eo[r2] = (float)(unsigned)(k2 & 0xFFFFFFFFu); dno[r2] = __uint_as_float((unsigned)(k2 >> 32)); }
        if (r3 < TOPK) { eo[r3] = (float)(unsigned)(k3 & 0xFFFFFFFFu); dno[r3] = __uint_as_float((unsigned)(k3 >> 32)); }
    } else {
        // ---- fallback: wave-iterative exact argmin from registers (rare) ----
        ull last = 0ULL;
        for (int k = 0; k < TOPK; ++k) {
            ull best = ~0ULL;
            #pragma unroll
            for (int t = 0; t < 32; ++t) {
                ull key = ((ull)u[t] << 32) | (unsigned)(ln + 64 * t);
                if (key > last && key < best) best = key;
            }
            #pragma unroll
            for (int off = 32; off; off >>= 1) {
                ull o = __shfl_xor(best, off);
                if (o < best) best = o;
            }
            if (ln == 0) {
                eo[k]  = (float)(unsigned)(best & 0xFFFFFFFFu);
                dno[k] = __uint_as_float((unsigned)(best >> 32));
            }
            last = best;
        }
    }
}

// ---------------------------------------------------------------------------
// K3 (v4, identical to R15 -- ~54 us): edge features -> MFMA 32x128 ->
// LayerNorm -> LDS transpose -> 1KB-contiguous nontemporal stores.
// ---------------------------------------------------------------------------
__global__ __launch_bounds__(256) void edge_kernel(
    const float* __restrict__ eidx, const float* __restrict__ dnb,
    const float* __restrict__ We, const float* __restrict__ be,
    const float* __restrict__ ge, const float* __restrict__ bte,
    float* __restrict__ E)
{
    __shared__ float ebuf[4][16][132];             // 33 KB
    const int lane = threadIdx.x & 63;
    const int wv   = threadIdx.x >> 6;
    const int c    = lane & 15;
    const int g    = lane >> 4;
    const int wid  = (int)((blockIdx.x * blockDim.x + threadIdx.x) >> 6);
    const int nw   = (int)((gridDim.x * blockDim.x) >> 6);

    short8v W[8];
    #pragma unroll
    for (int t = 0; t < 8; ++t)
        #pragma unroll
        for (int e = 0; e < 8; ++e)
            W[t][e] = f2bf(We[(g * 8 + e) * NH + t * 16 + c]);

    float fcs[8];
    #pragma unroll
    for (int e = 0; e < 8; ++e) {
        if (g < 2) fcs[e] = expf((float)(2 * e) * -0.57564627f);  // ln(1e4)/16
        else       fcs[e] = (float)((g - 2) * 8 + e) * (20.0f / 15.0f);
    }

    const int ntiles = NB * NL * TOPK / 16;
    for (int tile = wid; tile < ntiles; tile += nw) {
        const int e0   = tile * 16;
        const int edge = e0 + c;
        const float fidx = eidx[edge];
        const float Dv   = dnb[edge];
        const int   row  = edge / TOPK;
        const float d    = fidx - (float)(row & (NL - 1));

        short8v F;
        if (g == 0) {
            #pragma unroll
            for (int e = 0; e < 8; ++e) F[e] = f2bf(cosf(d * fcs[e]));
        } else if (g == 1) {
            #pragma unroll
            for (int e = 0; e < 8; ++e) F[e] = f2bf(sinf(d * fcs[e]));
        } else {
            #pragma unroll
            for (int e = 0; e < 8; ++e) {
                float tt = (Dv - fcs[e]) * 0.8f;
                F[e] = f2bf(expf(-tt * tt));
            }
        }

        f32x4 acc[8];
        const f32x4 zero = {0.0f, 0.0f, 0.0f, 0.0f};
        #pragma unroll
        for (int t = 0; t < 8; ++t)
            acc[t] = __builtin_amdgcn_mfma_f32_16x16x32_bf16(W[t], F, zero, 0, 0, 0);

        float s = 0.0f, s2 = 0.0f;
        #pragma unroll
        for (int t = 0; t < 8; ++t) {
            const f32x4 b4 = *(const f32x4*)&be[t * 16 + g * 4];
            #pragma unroll
            for (int j = 0; j < 4; ++j) {
                float vv = acc[t][j] + b4[j];
                acc[t][j] = vv;
                s  += vv;
                s2 = fmaf(vv, vv, s2);
            }
        }
        s  += __shfl_xor(s, 16);  s  += __shfl_xor(s, 32);
        s2 += __shfl_xor(s2, 16); s2 += __shfl_xor(s2, 32);
        const float mean = s * (1.0f / 128.0f);
        const float var  = fmaxf(s2 * (1.0f / 128.0f) - mean * mean, 0.0f);
        const float inv  = rsqrtf(var + 1e-5f);

        #pragma unroll
        for (int t = 0; t < 8; ++t) {
            const f32x4 g4  = *(const f32x4*)&ge [t * 16 + g * 4];
            const f32x4 bt4 = *(const f32x4*)&bte[t * 16 + g * 4];
            f32x4 o;
            #pragma unroll
            for (int j = 0; j < 4; ++j)
                o[j] = (acc[t][j] - mean) * inv * g4[j] + bt4[j];
            *(f32x4*)&ebuf[wv][c][t * 16 + g * 4] = o;
        }

        float* const Ebase = E + (size_t)e0 * NH;
        #pragma unroll
        for (int q = 0; q < 8; ++q) {
            const int fi = q * 256 + lane * 4;
            const int ce = fi >> 7;
            const int id = fi & 127;
            const f32x4 o = *(const f32x4*)&ebuf[wv][ce][id];
            __builtin_nontemporal_store(o, (f32x4*)&Ebase[(size_t)ce * NH + id]);
        }
    }
}

extern "C" void kernel_launch(void* const* d_in, const int* in_sizes, int n_in,
                              void* d_out, int out_size, void* d_ws, size_t ws_size,
                              hipStream_t stream)
{
    const float* X    = (const float*)d_in[0];
    const float* mask = (const float*)d_in[1];
    const float* Wn   = (const float*)d_in[2];
    const float* bn   = (const float*)d_in[3];
    const float* We   = (const float*)d_in[4];
    const float* be   = (const float*)d_in[5];
    const float* gn   = (const float*)d_in[6];
    const float* btn  = (const float*)d_in[7];
    const float* ge   = (const float*)d_in[8];
    const float* bte  = (const float*)d_in[9];

    float* out = (float*)d_out;
    float* V   = out;                                   // (8,2048,128)
    float* E   = V  + (size_t)NB * NL * NH;             // (8,2048,30,128)
    float* EI  = E  + (size_t)NB * NL * TOPK * NH;      // (8,2048,30) as float

    float4* P  = (float4*)d_ws;                         // SoA (x,y,z,m), 256 KB
    float* dnb = (float*)d_ws + 4 * (size_t)NB * NL;    // D_neighbors scratch

    hipLaunchKernelGGL(vnx_kernel,  dim3(NB * NL / 64),  dim3(256), 0, stream,
                       X, mask, Wn, bn, gn, btn, V, P);
    hipLaunchKernelGGL(topk_kernel, dim3(NB * NL / 4),   dim3(256), 0, stream,
                       P, EI, dnb);
    hipLaunchKernelGGL(edge_kernel, dim3(1920),          dim3(256), 0, stream,
                       EI, dnb, We, be, ge, bte, E);
}

// Round 17
// 113.402 us; speedup vs baseline: 2.7942x; 1.0620x over previous
//
#include <hip/hip_runtime.h>
#include <cstdint>
#include <cstddef>

#define NB 8
#define NL 2048
#define TOPK 30
#define NH 128
#define CAND_CAP 256
#define EDGE_BLOCKS 1920
#define EDGE_WAVES (EDGE_BLOCKS * 4)

typedef unsigned long long ull;
typedef __attribute__((ext_vector_type(8))) short short8v;   // 8 bf16
typedef __attribute__((ext_vector_type(4))) float f32x4;

__device__ __forceinline__ short f2bf(float f) {
    unsigned int b = __float_as_uint(f);
    b += 0x7fffu + ((b >> 16) & 1u);          // round-to-nearest-even
    return (short)(b >> 16);
}

// ---------------------------------------------------------------------------
// K1 (topk v9): 512-thread blocks; 8 rows share ONE 32 KB LDS stage, loaded
// straight from X+mask (same values as old P -> bit-identical distances; the
// P/xpose pipeline stage is eliminated). Selection logic byte-identical to
// v7/v8: bitonic lane-min threshold, ballot compaction, rank-based exact
// selection; key=(bits<<32)|j == lax.top_k stable order; exact fallback.
// LDS 48 KB -> 3 blocks/CU = 24 waves/CU (was 16).
// ---------------------------------------------------------------------------
__global__ __launch_bounds__(512) void topk_kernel(
    const float* __restrict__ X, const float* __restrict__ mask,
    float* __restrict__ eidx, float* __restrict__ dnb)
{
    __shared__ float4 Ps[NL];                      // 32 KB
    __shared__ ull cand[8][CAND_CAP];              // 16 KB

    const int tid = threadIdx.x;
    const int wv  = tid >> 6;                      // 0..7
    const int ln  = tid & 63;
    const int row = blockIdx.x * 8 + wv;           // 8 rows per block
    const int b   = row >> 11;
    const int i   = row & (NL - 1);

    // ---- stage CA coords + mask from X (the block's only barrier) ----
    const float* Xb = X + (size_t)b * NL * 12;
    const float* Mb = mask + (size_t)b * NL;
    #pragma unroll
    for (int q = 0; q < 4; ++q) {
        const int j = tid + 512 * q;
        const float* x = Xb + (size_t)j * 12 + 3;
        Ps[j] = make_float4(x[0], x[1], x[2], Mb[j]);
    }
    __syncthreads();

    const float4 pi = Ps[i];
    const float xi = pi.x, yi = pi.y, zi = pi.z, mi = pi.w;

    // ---- P1: distances once from LDS; mask flag in sign bit; 4-way chains --
    unsigned int u[32];
    float lm0 = 0.0f, lm1 = 0.0f, lm2 = 0.0f, lm3 = 0.0f;
    #pragma unroll
    for (int t = 0; t < 32; t += 4) {
        #pragma unroll
        for (int q = 0; q < 4; ++q) {
            const float4 pj = Ps[ln + 64 * (t + q)];
            float dx = xi - pj.x;
            float dy = yi - pj.y;
            float dz = zi - pj.z;
            float s = __fadd_rn(__fmul_rn(dx, dx), __fmul_rn(dy, dy));
            s = __fadd_rn(s, __fmul_rn(dz, dz));
            s = __fadd_rn(s, 1e-6f);
            float m2 = __fmul_rn(pj.w, mi);
            float d  = __fmul_rn(m2, __fsqrt_rn(s));
            u[t + q] = __float_as_uint(d) | ((m2 == 0.0f) ? 0x80000000u : 0u);
            if      (q == 0) lm0 = fmaxf(lm0, d);
            else if (q == 1) lm1 = fmaxf(lm1, d);
            else if (q == 2) lm2 = fmaxf(lm2, d);
            else             lm3 = fmaxf(lm3, d);
        }
    }
    float lmax = fmaxf(fmaxf(lm0, lm1), fmaxf(lm2, lm3));
    #pragma unroll
    for (int off = 32; off; off >>= 1) lmax = fmaxf(lmax, __shfl_xor(lmax, off));
    const unsigned int DMB = __float_as_uint(__fadd_rn(lmax, 1.0f));

    // ---- P2: adjusted bits via select + per-lane min (4-way chains) ----
    unsigned int um0 = 0xFFFFFFFFu, um1 = 0xFFFFFFFFu,
                 um2 = 0xFFFFFFFFu, um3 = 0xFFFFFFFFu;
    #pragma unroll
    for (int t = 0; t < 32; t += 4) {
        unsigned int b0 = (u[t+0] & 0x80000000u) ? DMB : u[t+0];
        unsigned int b1 = (u[t+1] & 0x80000000u) ? DMB : u[t+1];
        unsigned int b2 = (u[t+2] & 0x80000000u) ? DMB : u[t+2];
        unsigned int b3 = (u[t+3] & 0x80000000u) ? DMB : u[t+3];
        u[t+0] = b0; u[t+1] = b1; u[t+2] = b2; u[t+3] = b3;
        um0 = min(um0, b0); um1 = min(um1, b1);
        um2 = min(um2, b2); um3 = min(um3, b3);
    }
    unsigned int umin = min(min(um0, um1), min(um2, um3));

    // ---- P3: bitonic sort of 64 lane-minima -> threshold T at rank 29 ----
    unsigned int v = umin;
    #pragma unroll
    for (int k = 2; k <= 64; k <<= 1) {
        #pragma unroll
        for (int j = k >> 1; j > 0; j >>= 1) {
            unsigned int o = __shfl_xor(v, j);
            bool asc   = ((ln & k) == 0);
            bool lower = ((ln & j) == 0);
            v = (lower == asc) ? min(v, o) : max(v, o);
        }
    }
    const unsigned int T = __shfl(v, TOPK - 1);

    // ---- P4: ordered ballot compaction ----
    unsigned int base = 0;
    #pragma unroll
    for (int t = 0; t < 32; ++t) {
        bool act = u[t] <= T;
        ull m = __ballot(act);
        if (act) {
            unsigned int pos = base + (unsigned)__popcll(m & ((1ull << ln) - 1ull));
            if (pos < CAND_CAP)
                cand[wv][pos] = ((ull)u[t] << 32) | (unsigned)(ln + 64 * t);
        }
        base += (unsigned)__popcll(m);
    }
    const unsigned int cnt = base;

    float* eo  = eidx + (size_t)row * TOPK;
    float* dno = dnb  + (size_t)row * TOPK;

    if (cnt <= CAND_CAP) {
        // ---- P5: rank-based exact selection, unrolled x4 ----
        ull k0 = ((unsigned)ln        < cnt) ? cand[wv][ln]        : ~0ULL;
        ull k1 = ((unsigned)ln +  64u < cnt) ? cand[wv][ln +  64]  : ~0ULL;
        ull k2 = ((unsigned)ln + 128u < cnt) ? cand[wv][ln + 128]  : ~0ULL;
        ull k3 = ((unsigned)ln + 192u < cnt) ? cand[wv][ln + 192]  : ~0ULL;
        int r0 = 0, r1 = 0, r2 = 0, r3 = 0;
        for (unsigned int p = 0; p < cnt; p += 4) {
            ull c0 = cand[wv][p];
            ull c1 = (p + 1 < cnt) ? cand[wv][p + 1] : ~0ULL;
            ull c2 = (p + 2 < cnt) ? cand[wv][p + 2] : ~0ULL;
            ull c3 = (p + 3 < cnt) ? cand[wv][p + 3] : ~0ULL;
            r0 += (c0 < k0) + (c1 < k0) + (c2 < k0) + (c3 < k0);
            r1 += (c0 < k1) + (c1 < k1) + (c2 < k1) + (c3 < k1);
            r2 += (c0 < k2) + (c1 < k2) + (c2 < k2) + (c3 < k2);
            r3 += (c0 < k3) + (c1 < k3) + (c2 < k3) + (c3 < k3);
        }
        if (r0 < TOPK) { eo[r0] = (float)(unsigned)(k0 & 0xFFFFFFFFu); dno[r0] = __uint_as_float((unsigned)(k0 >> 32)); }
        if (r1 < TOPK) { eo[r1] = (float)(unsigned)(k1 & 0xFFFFFFFFu); dno[r1] = __uint_as_float((unsigned)(k1 >> 32)); }
        if (r2 < TOPK) { eo[r2] = (float)(unsigned)(k2 & 0xFFFFFFFFu); dno[r2] = __uint_as_float((unsigned)(k2 >> 32)); }
        if (r3 < TOPK) { eo[r3] = (float)(unsigned)(k3 & 0xFFFFFFFFu); dno[r3] = __uint_as_float((unsigned)(k3 >> 32)); }
    } else {
        // ---- fallback: wave-iterative exact argmin from registers (rare) ----
        ull last = 0ULL;
        for (int k = 0; k < TOPK; ++k) {
            ull best = ~0ULL;
            #pragma unroll
            for (int t = 0; t < 32; ++t) {
                ull key = ((ull)u[t] << 32) | (unsigned)(ln + 64 * t);
                if (key > last && key < best) best = key;
            }
            #pragma unroll
            for (int off = 32; off; off >>= 1) {
                ull o = __shfl_xor(best, off);
                if (o < best) best = o;
            }
            if (ln == 0) {
                eo[k]  = (float)(unsigned)(best & 0xFFFFFFFFu);
                dno[k] = __uint_as_float((unsigned)(best >> 32));
            }
            last = best;
        }
    }
}

// ---------------------------------------------------------------------------
// K2 (edge ∪ vn, grid-fused): blocks [0,1920) = edge path (v4, nw hardcoded
// 7680 -- byte-identical math); blocks [1920,2176) = vn path (v4 logic:
// wave-0 node-per-lane dihedrals + quadratic-form LN stats, barrier, all 4
// waves coalesced V stores; P write removed). The two paths touch disjoint
// outputs and vn depends only on X/weights, so block order is irrelevant.
// ---------------------------------------------------------------------------
__global__ __launch_bounds__(256) void edge_vn_kernel(
    const float* __restrict__ eidx, const float* __restrict__ dnb,
    const float* __restrict__ We, const float* __restrict__ be,
    const float* __restrict__ ge, const float* __restrict__ bte,
    float* __restrict__ E,
    const float* __restrict__ X,  const float* __restrict__ Wn,
    const float* __restrict__ bn, const float* __restrict__ gn,
    const float* __restrict__ btn, float* __restrict__ V)
{
    __shared__ float shmem[4 * 16 * 132];          // 33 KB (edge) / 2 KB (vn)

    const int tid  = threadIdx.x;
    const int lane = tid & 63;
    const int wv   = tid >> 6;

    if (blockIdx.x < EDGE_BLOCKS) {
        // ========================== EDGE PATH ==============================
        float (*ebuf)[132] = (float(*)[132])(shmem + wv * 16 * 132);
        const int c = lane & 15;
        const int g = lane >> 4;
        const int wid = blockIdx.x * 4 + wv;

        short8v W[8];
        #pragma unroll
        for (int t = 0; t < 8; ++t)
            #pragma unroll
            for (int e = 0; e < 8; ++e)
                W[t][e] = f2bf(We[(g * 8 + e) * NH + t * 16 + c]);

        float fcs[8];
        #pragma unroll
        for (int e = 0; e < 8; ++e) {
            if (g < 2) fcs[e] = expf((float)(2 * e) * -0.57564627f);  // ln(1e4)/16
            else       fcs[e] = (float)((g - 2) * 8 + e) * (20.0f / 15.0f);
        }

        const int ntiles = NB * NL * TOPK / 16;
        for (int tile = wid; tile < ntiles; tile += EDGE_WAVES) {
            const int e0   = tile * 16;
            const int edge = e0 + c;
            const float fidx = eidx[edge];
            const float Dv   = dnb[edge];
            const int   row  = edge / TOPK;
            const float d    = fidx - (float)(row & (NL - 1));

            short8v F;
            if (g == 0) {
                #pragma unroll
                for (int e = 0; e < 8; ++e) F[e] = f2bf(cosf(d * fcs[e]));
            } else if (g == 1) {
                #pragma unroll
                for (int e = 0; e < 8; ++e) F[e] = f2bf(sinf(d * fcs[e]));
            } else {
                #pragma unroll
                for (int e = 0; e < 8; ++e) {
                    float tt = (Dv - fcs[e]) * 0.8f;
                    F[e] = f2bf(expf(-tt * tt));
                }
            }

            f32x4 acc[8];
            const f32x4 zero = {0.0f, 0.0f, 0.0f, 0.0f};
            #pragma unroll
            for (int t = 0; t < 8; ++t)
                acc[t] = __builtin_amdgcn_mfma_f32_16x16x32_bf16(W[t], F, zero, 0, 0, 0);

            float s = 0.0f, s2 = 0.0f;
            #pragma unroll
            for (int t = 0; t < 8; ++t) {
                const f32x4 b4 = *(const f32x4*)&be[t * 16 + g * 4];
                #pragma unroll
                for (int j = 0; j < 4; ++j) {
                    float vv = acc[t][j] + b4[j];
                    acc[t][j] = vv;
                    s  += vv;
                    s2 = fmaf(vv, vv, s2);
                }
            }
            s  += __shfl_xor(s, 16);  s  += __shfl_xor(s, 32);
            s2 += __shfl_xor(s2, 16); s2 += __shfl_xor(s2, 32);
            const float mean = s * (1.0f / 128.0f);
            const float var  = fmaxf(s2 * (1.0f / 128.0f) - mean * mean, 0.0f);
            const float inv  = rsqrtf(var + 1e-5f);

            #pragma unroll
            for (int t = 0; t < 8; ++t) {
                const f32x4 g4  = *(const f32x4*)&ge [t * 16 + g * 4];
                const f32x4 bt4 = *(const f32x4*)&bte[t * 16 + g * 4];
                f32x4 o;
                #pragma unroll
                for (int j = 0; j < 4; ++j)
                    o[j] = (acc[t][j] - mean) * inv * g4[j] + bt4[j];
                *(f32x4*)&ebuf[c][t * 16 + g * 4] = o;
            }

            float* const Ebase = E + (size_t)e0 * NH;
            #pragma unroll
            for (int q = 0; q < 8; ++q) {
                const int fi = q * 256 + lane * 4;
                const int ce = fi >> 7;
                const int id = fi & 127;
                const f32x4 o = *(const f32x4*)&ebuf[ce][id];
                __builtin_nontemporal_store(o, (f32x4*)&Ebase[(size_t)ce * NH + id]);
            }
        }
        return;
    }

    // ============================ VN PATH ==================================
    float (*fsh)[8] = (float(*)[8])shmem;          // [64][8]
    const int node_base = (blockIdx.x - EDGE_BLOCKS) * 64;

    if (tid < 64) {
        const int ln   = tid;
        const int node = node_base + ln;
        const int b = node >> 11, i = node & (NL - 1);

        const int h0 = ln, h1 = ln + 64;
        float w0[6], w1[6];
        #pragma unroll
        for (int j = 0; j < 6; ++j) { w0[j] = Wn[j * NH + h0]; w1[j] = Wn[j * NH + h1]; }
        const float bb0 = bn[h0], bb1 = bn[h1];

        // Phase 0: wave-reduce LN stats (35 values)
        float st[35];
        {
            int idx = 0;
            #pragma unroll
            for (int j = 0; j < 6; ++j)
                #pragma unroll
                for (int k = j; k < 6; ++k)
                    st[idx++] = w0[j] * w0[k] + w1[j] * w1[k];
            #pragma unroll
            for (int j = 0; j < 6; ++j) st[21 + j] = w0[j] * bb0 + w1[j] * bb1;
            #pragma unroll
            for (int j = 0; j < 6; ++j) st[27 + j] = w0[j] + w1[j];
            st[33] = bb0 + bb1;
            st[34] = bb0 * bb0 + bb1 * bb1;
            #pragma unroll
            for (int q = 0; q < 35; ++q) {
                float vv = st[q];
                #pragma unroll
                for (int off = 32; off; off >>= 1) vv += __shfl_xor(vv, off);
                st[q] = vv;
            }
        }

        // Phase 1: dihedrals for THIS lane's node
        const float* XB = X + (size_t)b * NL * 12;
        const int rm1 = (i >= 1) ? i - 1 : 0;
        const int rp1 = (i <= NL - 2) ? i + 1 : NL - 1;
        float p[6][3];
        {
            const int rows[6]  = { rm1, i, i, i, rp1, rp1 };
            const int atoms[6] = { 2,   0, 1, 2, 0,   1   };
            #pragma unroll
            for (int k = 0; k < 6; ++k) {
                const float* q = XB + ((size_t)rows[k] * 4 + atoms[k]) * 3;
                p[k][0] = q[0]; p[k][1] = q[1]; p[k][2] = q[2];
            }
        }
        float uv[5][3], nv[4][3];
        #pragma unroll
        for (int k = 0; k < 5; ++k) {
            float vx = p[k+1][0] - p[k][0];
            float vy = p[k+1][1] - p[k][1];
            float vz = p[k+1][2] - p[k][2];
            float n = sqrtf(vx*vx + vy*vy + vz*vz) + 1e-8f;
            uv[k][0] = vx / n; uv[k][1] = vy / n; uv[k][2] = vz / n;
        }
        #pragma unroll
        for (int k = 0; k < 4; ++k) {
            float cx = uv[k][1]*uv[k+1][2] - uv[k][2]*uv[k+1][1];
            float cy = uv[k][2]*uv[k+1][0] - uv[k][0]*uv[k+1][2];
            float cz = uv[k][0]*uv[k+1][1] - uv[k][1]*uv[k+1][0];
            float n = sqrtf(cx*cx + cy*cy + cz*cz) + 1e-8f;
            nv[k][0] = cx / n; nv[k][1] = cy / n; nv[k][2] = cz / n;
        }
        float f[6];
        #pragma unroll
        for (int a = 0; a < 3; ++a) {
            bool valid = (a == 0) ? (i >= 1) : (i <= NL - 2);
            float cosD = nv[a][0]*nv[a+1][0] + nv[a][1]*nv[a+1][1] + nv[a][2]*nv[a+1][2];
            cosD = fminf(fmaxf(cosD, -1.0f + 1e-7f), 1.0f - 1e-7f);
            float sg = uv[a][0]*nv[a+1][0] + uv[a][1]*nv[a+1][1] + uv[a][2]*nv[a+1][2];
            float sgn = (sg > 0.0f) ? 1.0f : ((sg < 0.0f) ? -1.0f : 0.0f);
            float an = valid ? (sgn * acosf(cosD)) : 0.0f;
            f[a]     = cosf(an);
            f[3 + a] = sinf(an);
        }

        float s1 = st[33];
        #pragma unroll
        for (int j = 0; j < 6; ++j) s1 = fmaf(f[j], st[27 + j], s1);
        float qd = st[34];
        #pragma unroll
        for (int j = 0; j < 6; ++j) qd = fmaf(2.0f * f[j], st[21 + j], qd);
        {
            int idx = 0;
            #pragma unroll
            for (int j = 0; j < 6; ++j)
                #pragma unroll
                for (int k = j; k < 6; ++k) {
                    float coef = (j == k) ? 1.0f : 2.0f;
                    qd = fmaf(coef * f[j] * f[k], st[idx], qd);
                    ++idx;
                }
        }
        const float mean = s1 * (1.0f / 128.0f);
        const float var  = fmaxf(qd * (1.0f / 128.0f) - mean * mean, 0.0f);
        const float inv  = rsqrtf(var + 1e-5f);

        #pragma unroll
        for (int j = 0; j < 6; ++j) fsh[ln][j] = f[j];
        fsh[ln][6] = mean;
        fsh[ln][7] = inv;
    }
    __syncthreads();

    // Phase 2: all 256 threads; 4 h-cols each; coalesced f32x4 stores
    const int m  = tid & 31;
    const int ng = tid >> 5;
    const int h4 = m * 4;
    f32x4 w4[6];
    #pragma unroll
    for (int j = 0; j < 6; ++j) w4[j] = *(const f32x4*)&Wn[j * NH + h4];
    const f32x4 b4  = *(const f32x4*)&bn [h4];
    const f32x4 g4  = *(const f32x4*)&gn [h4];
    const f32x4 bt4 = *(const f32x4*)&btn[h4];

    #pragma unroll
    for (int it = 0; it < 8; ++it) {
        const int nn = it * 8 + ng;
        const float* fr = fsh[nn];
        f32x4 a = b4;
        #pragma unroll
        for (int j = 0; j < 6; ++j) {
            const float fj = fr[j];
            #pragma unroll
            for (int x = 0; x < 4; ++x) a[x] = fmaf(fj, w4[j][x], a[x]);
        }
        const float mn = fr[6], iv = fr[7];
        f32x4 o;
        #pragma unroll
        for (int x = 0; x < 4; ++x) o[x] = (a[x] - mn) * iv * g4[x] + bt4[x];
        *(f32x4*)&V[(size_t)(node_base + nn) * NH + h4] = o;
    }
}

extern "C" void kernel_launch(void* const* d_in, const int* in_sizes, int n_in,
                              void* d_out, int out_size, void* d_ws, size_t ws_size,
                              hipStream_t stream)
{
    const float* X    = (const float*)d_in[0];
    const float* mask = (const float*)d_in[1];
    const float* Wn   = (const float*)d_in[2];
    const float* bn   = (const float*)d_in[3];
    const float* We   = (const float*)d_in[4];
    const float* be   = (const float*)d_in[5];
    const float* gn   = (const float*)d_in[6];
    const float* btn  = (const float*)d_in[7];
    const float* ge   = (const float*)d_in[8];
    const float* bte  = (const float*)d_in[9];

    float* out = (float*)d_out;
    float* V   = out;                                   // (8,2048,128)
    float* E   = V  + (size_t)NB * NL * NH;             // (8,2048,30,128)
    float* EI  = E  + (size_t)NB * NL * TOPK * NH;      // (8,2048,30) as float

    float* dnb = (float*)d_ws;                          // D_neighbors scratch

    hipLaunchKernelGGL(topk_kernel,    dim3(NB * NL / 8),      dim3(512), 0, stream,
                       X, mask, EI, dnb);
    hipLaunchKernelGGL(edge_vn_kernel, dim3(EDGE_BLOCKS + 256), dim3(256), 0, stream,
                       EI, dnb, We, be, ge, bte, E, X, Wn, bn, gn, btn, V);
}